// Round 2
// baseline (2382.637 us; speedup 1.0000x reference)
//
#include <hip/hip_runtime.h>
#include <cstddef>

constexpr int Bn    = 8;
constexpr int Hn    = 96;
constexpr int Wn    = 96;
constexpr int HWn   = Hn * Wn;       // 9216
constexpr int BHWn  = Bn * HWn;      // 73728
constexpr int B10HW = Bn * 10 * HWn; // 737280

// ---------------------------------------------------------------------------
// K1: decomp_att conv3x3 257->256 (+BN+ReLU) fused with conv1x1 256->2.
// Tile: 128 cout x (2 rows x 32 cols). Block 256 threads.
// grid.x = B * (H/2) * (W/32) = 8*48*3 = 1152, grid.y = 2 (cout halves).
// 1x1 partials reduced in LDS, then fp32 atomicAdd into dm_acc (workspace).
// ---------------------------------------------------------------------------
__global__ __launch_bounds__(256)
void k_bigconv(const float* __restrict__ xh, const float* __restrict__ patt,
               const float* __restrict__ w1, const float* __restrict__ g1,
               const float* __restrict__ b1, const float* __restrict__ w2,
               float* __restrict__ dm_acc)
{
    __shared__ float xs[8][4][34];                  // [ci][row h0-1..h0+2][w0-1..w0+32]
    __shared__ __align__(16) float wl[8 * 9 * 128]; // [ci][tap][co]
    __shared__ float dml[2][64];                    // 1x1 partials: [j][2 rows x 32 w]

    const int tid  = threadIdx.x;
    const int sb   = blockIdx.x;
    const int wseg = sb % 3;
    const int hb   = (sb / 3) % 48;
    const int b    = sb / (3 * 48);
    const int h0   = hb * 2, w0 = wseg * 32;
    const int co0  = blockIdx.y * 128;

    const int cog = tid >> 3;   // 0..31 -> co = co0 + cog*4 + (0..3)
    const int pg  = tid & 7;
    const int r   = pg >> 2;    // output row within tile (0/1)
    const int wg  = pg & 3;     // positions w0 + wg*8 + (0..7)

    if (tid < 128) dml[tid >> 6][tid & 63] = 0.f;

    float acc[4][8] = {};

    for (int cin0 = 0; cin0 < 264; cin0 += 8) {   // 33 chunks cover 257 cin (zero-padded)
        __syncthreads();
        // stage x patch: 8*4*34 = 1088 values
        for (int idx = tid; idx < 1088; idx += 256) {
            int ci = idx / 136, rem = idx % 136, row = rem / 34, wloc = rem % 34;
            int c = cin0 + ci, hh = h0 - 1 + row, ww = w0 - 1 + wloc;
            float v = 0.f;
            if (c < 257 && (unsigned)hh < (unsigned)Hn && (unsigned)ww < (unsigned)Wn) {
                v = (c == 0) ? patt[b * HWn + hh * Wn + ww]
                             : xh[((size_t)b * 256 + (c - 1)) * HWn + hh * Wn + ww];
            }
            xs[ci][row][wloc] = v;
        }
        // stage weights: 8*9*128 = 9216 values, layout [ci][tap][co]
        for (int idx = tid; idx < 9216; idx += 256) {
            int ci = idx / 1152, rem = idx % 1152, tap = rem / 128, co = rem % 128;
            int c = cin0 + ci;
            wl[idx] = (c < 257) ? w1[((size_t)(co0 + co) * 257 + c) * 9 + tap] : 0.f;
        }
        __syncthreads();

        #pragma unroll
        for (int ci = 0; ci < 8; ++ci) {
            #pragma unroll
            for (int kh = 0; kh < 3; ++kh) {
                float xr[10];
                const float* xp = &xs[ci][r + kh][wg * 8];
                #pragma unroll
                for (int k = 0; k < 10; ++k) xr[k] = xp[k];
                #pragma unroll
                for (int kw = 0; kw < 3; ++kw) {
                    const float4 wv =
                        *(const float4*)&wl[(ci * 9 + kh * 3 + kw) * 128 + cog * 4];
                    #pragma unroll
                    for (int k = 0; k < 8; ++k) {
                        const float xv = xr[k + kw];
                        acc[0][k] = fmaf(wv.x, xv, acc[0][k]);
                        acc[1][k] = fmaf(wv.y, xv, acc[1][k]);
                        acc[2][k] = fmaf(wv.z, xv, acc[2][k]);
                        acc[3][k] = fmaf(wv.w, xv, acc[3][k]);
                    }
                }
            }
        }
    }

    // epilogue: BN + ReLU, then 1x1 (256->2) partial reduction
    float gv[4], bv[4], w2a[4], w2b[4];
    #pragma unroll
    for (int j = 0; j < 4; ++j) {
        int co = co0 + cog * 4 + j;
        gv[j]  = g1[co];
        bv[j]  = b1[co];
        w2a[j] = w2[co];
        w2b[j] = w2[256 + co];
    }
    #pragma unroll
    for (int k = 0; k < 8; ++k) {
        float s0 = 0.f, s1 = 0.f;
        #pragma unroll
        for (int j = 0; j < 4; ++j) {
            float y = fmaf(acc[j][k], gv[j], bv[j]);
            y = fmaxf(y, 0.f);
            s0 = fmaf(w2a[j], y, s0);
            s1 = fmaf(w2b[j], y, s1);
        }
        atomicAdd(&dml[0][r * 32 + wg * 8 + k], s0);
        atomicAdd(&dml[1][r * 32 + wg * 8 + k], s1);
    }
    __syncthreads();
    if (tid < 128) {
        int j = tid >> 6, pos = tid & 63, rr = pos >> 5, ww = pos & 31;
        atomicAdd(&dm_acc[((size_t)b * 2 + j) * HWn + (h0 + rr) * Wn + (w0 + ww)],
                  dml[j][pos]);
    }
}

// ---------------------------------------------------------------------------
// K2: dm = acc + bias (written to d_out), s_i = softmax(dm)_i * parent_att
// ---------------------------------------------------------------------------
__global__ void k_dm_soft(const float* __restrict__ dm_acc, const float* __restrict__ db2,
                          const float* __restrict__ patt, float* __restrict__ dm_out,
                          float* __restrict__ s01)
{
    const int p = blockIdx.x * 256 + threadIdx.x;
    if (p >= BHWn) return;
    const int b = p / HWn, hw = p % HWn;
    const size_t i0 = (size_t)(b * 2) * HWn + hw;
    const size_t i1 = (size_t)(b * 2 + 1) * HWn + hw;
    float d0 = dm_acc[i0] + db2[0];
    float d1 = dm_acc[i1] + db2[1];
    dm_out[i0] = d0;
    dm_out[i1] = d1;
    float m  = fmaxf(d0, d1);
    float e0 = expf(d0 - m), e1 = expf(d1 - m);
    float pa = patt[p];
    float inv = pa / (e0 + e1);
    s01[p]        = e0 * inv;
    s01[BHWn + p] = e1 * inv;
}

// ---------------------------------------------------------------------------
// K3: up = sum(p_nodes[1:5]) * sum(p_atts[1:5]); lo = sum(p_nodes[5:7]) * sum(p_atts[5:7])
// ---------------------------------------------------------------------------
__global__ void k_uplo(const float* __restrict__ pn, const float* __restrict__ pa,
                       float* __restrict__ up, float* __restrict__ lo)
{
    const int p = blockIdx.x * 256 + threadIdx.x;
    if (p >= BHWn) return;
    const int b = p / HWn, hw = p % HWn;
    float au = 0.f, al = 0.f;
    for (int k = 1; k <= 4; ++k) au += pa[(size_t)(k * Bn + b) * HWn + hw];
    for (int k = 5; k <= 6; ++k) al += pa[(size_t)(k * Bn + b) * HWn + hw];
    for (int c = 0; c < 10; ++c) {
        float su = 0.f, sl = 0.f;
        for (int k = 1; k <= 4; ++k) su += pn[((size_t)(k * Bn + b) * 10 + c) * HWn + hw];
        for (int k = 5; k <= 6; ++k) sl += pn[((size_t)(k * Bn + b) * 10 + c) * HWn + hw];
        up[((size_t)b * 10 + c) * HWn + hw] = su * au;
        lo[((size_t)b * 10 + c) * HWn + hw] = sl * al;
    }
}

// ---------------------------------------------------------------------------
// K4: branch = ReLU(BN(conv3x3 20->10)) -> ReLU(BN(conv1x1 10->10))
// z = 0: decomp0 [parent*s0, h1]   (rel weights)
// z = 1: decomp1 [parent*s1, h2]   (rel weights)
// z = 2: comp_u  [h1, up]          (cu weights)
// z = 3: comp_l  [h2, lo]          (cl weights)
// ---------------------------------------------------------------------------
struct BranchW  { const float *w1, *g1, *b1, *w2, *g2, *b2; };
struct BranchW3 { BranchW p[3]; };

__global__ __launch_bounds__(256)
void k_branch(BranchW3 P, const float* __restrict__ parent, const float* __restrict__ h_nodes,
              const float* __restrict__ s01, const float* __restrict__ up,
              const float* __restrict__ lo, float* __restrict__ bout)
{
    const int z  = blockIdx.z;
    const int pi = (z < 2) ? 0 : (z - 1);
    __shared__ float wl[1800], w2l[100], g1l[10], b1l[10], g2l[10], b2l[10];
    const BranchW& Pw = P.p[pi];
    for (int i = threadIdx.x; i < 1800; i += 256) wl[i] = Pw.w1[i];
    if (threadIdx.x < 100) w2l[threadIdx.x] = Pw.w2[threadIdx.x];
    if (threadIdx.x < 10) {
        g1l[threadIdx.x] = Pw.g1[threadIdx.x];
        b1l[threadIdx.x] = Pw.b1[threadIdx.x];
        g2l[threadIdx.x] = Pw.g2[threadIdx.x];
        b2l[threadIdx.x] = Pw.b2[threadIdx.x];
    }
    __syncthreads();

    const int p = blockIdx.x * 256 + threadIdx.x;
    const int b = p / HWn, hw = p % HWn, h = hw / Wn, w = hw % Wn;

    const float* Ab = nullptr;
    const float* sc = nullptr;
    const float* Bb = nullptr;
    if (z == 0)      { Ab = parent; sc = s01;        Bb = h_nodes + (size_t)1 * B10HW; }
    else if (z == 1) { Ab = parent; sc = s01 + BHWn; Bb = h_nodes + (size_t)2 * B10HW; }
    else if (z == 2) { Ab = h_nodes + (size_t)1 * B10HW; Bb = up; }
    else             { Ab = h_nodes + (size_t)2 * B10HW; Bb = lo; }

    float acc[10] = {};
    for (int kh = 0; kh < 3; ++kh) {
        const int hh = h + kh - 1;
        if ((unsigned)hh >= (unsigned)Hn) continue;
        for (int kw = 0; kw < 3; ++kw) {
            const int ww = w + kw - 1;
            if ((unsigned)ww >= (unsigned)Wn) continue;
            const int off = hh * Wn + ww;
            const int tap = kh * 3 + kw;
            const float scv = sc ? sc[b * HWn + off] : 1.f;
            #pragma unroll
            for (int ci = 0; ci < 20; ++ci) {
                float v;
                if (ci < 10) v = Ab[((size_t)b * 10 + ci) * HWn + off] * scv;
                else         v = Bb[((size_t)b * 10 + (ci - 10)) * HWn + off];
                #pragma unroll
                for (int co = 0; co < 10; ++co)
                    acc[co] = fmaf(wl[(co * 20 + ci) * 9 + tap], v, acc[co]);
            }
        }
    }
    float y[10];
    #pragma unroll
    for (int co = 0; co < 10; ++co)
        y[co] = fmaxf(fmaf(acc[co], g1l[co], b1l[co]), 0.f);
    #pragma unroll
    for (int co = 0; co < 10; ++co) {
        float s = 0.f;
        #pragma unroll
        for (int i = 0; i < 10; ++i) s = fmaf(w2l[co * 10 + i], y[i], s);
        s = fmaxf(fmaf(s, g2l[co], b2l[co]), 0.f);
        bout[(size_t)z * B10HW + ((size_t)b * 10 + co) * HWn + hw] = s;
    }
}

// ---------------------------------------------------------------------------
// K5: ConvGRU (1x1 kernels). z = node 0/1/2.
// node0: x = f_nodes[0] + p_nodes[0]; node1: x = comp_u + decomp0; node2: x = comp_l + decomp1
// ---------------------------------------------------------------------------
__global__ void k_gru(const float* __restrict__ f_nodes, const float* __restrict__ h_nodes,
                      const float* __restrict__ p_nodes, const float* __restrict__ bout,
                      const float* __restrict__ gw, const float* __restrict__ gb,
                      const float* __restrict__ cw, const float* __restrict__ cg,
                      const float* __restrict__ cb, float* __restrict__ out)
{
    const int z = blockIdx.y;
    __shared__ float gwl[40], cwl[200], gbl[2], cgl[10], cbl[10];
    if (threadIdx.x < 40)  gwl[threadIdx.x] = gw[z * 40 + threadIdx.x];
    if (threadIdx.x < 200) cwl[threadIdx.x] = cw[z * 200 + threadIdx.x];
    if (threadIdx.x < 2)   gbl[threadIdx.x] = gb[z * 2 + threadIdx.x];
    if (threadIdx.x < 10) {
        cgl[threadIdx.x] = cg[z * 10 + threadIdx.x];
        cbl[threadIdx.x] = cb[z * 10 + threadIdx.x];
    }
    __syncthreads();

    const int p = blockIdx.x * 256 + threadIdx.x;
    const int b = p / HWn, hw = p % HWn;
    float x[10], h[10];
    #pragma unroll
    for (int c = 0; c < 10; ++c) {
        const size_t idx = ((size_t)b * 10 + c) * HWn + hw;
        if (z == 0)      x[c] = f_nodes[idx] + p_nodes[idx];
        else if (z == 1) x[c] = bout[(size_t)2 * B10HW + idx] + bout[idx];
        else             x[c] = bout[(size_t)3 * B10HW + idx] + bout[(size_t)1 * B10HW + idx];
        h[c] = h_nodes[(size_t)z * B10HW + idx];
    }
    float g0 = gbl[0], g1 = gbl[1];
    #pragma unroll
    for (int c = 0; c < 10; ++c) {
        g0 = fmaf(gwl[c],      x[c], g0);
        g0 = fmaf(gwl[10 + c], h[c], g0);
        g1 = fmaf(gwl[20 + c], x[c], g1);
        g1 = fmaf(gwl[30 + c], h[c], g1);
    }
    const float r = 1.f / (1.f + expf(-g0));
    const float u = 1.f / (1.f + expf(-g1));
    #pragma unroll
    for (int o = 0; o < 10; ++o) {
        float s = 0.f;
        #pragma unroll
        for (int c = 0; c < 10; ++c) {
            s = fmaf(cwl[o * 20 + c],      x[c],     s);
            s = fmaf(cwl[o * 20 + 10 + c], r * h[c], s);
        }
        s = fmaxf(fmaf(s, cgl[o], cbl[o]), 0.f);
        out[(size_t)z * B10HW + ((size_t)b * 10 + o) * HWn + hw] =
            (1.f - u) * h[o] + u * s;
    }
}

// ---------------------------------------------------------------------------
extern "C" void kernel_launch(void* const* d_in, const int* in_sizes, int n_in,
                              void* d_out, int out_size, void* d_ws, size_t ws_size,
                              hipStream_t stream)
{
    (void)in_sizes; (void)n_in; (void)out_size; (void)ws_size;

    const float* f_nodes = (const float*)d_in[0];
    const float* h_nodes = (const float*)d_in[1];
    const float* p_nodes = (const float*)d_in[2];
    const float* xh      = (const float*)d_in[3];
    const float* f_atts  = (const float*)d_in[4];
    const float* p_atts  = (const float*)d_in[5];
    const float* da_w1   = (const float*)d_in[6];
    const float* da_g1   = (const float*)d_in[7];
    const float* da_b1   = (const float*)d_in[8];
    const float* da_w2   = (const float*)d_in[9];
    const float* da_b2   = (const float*)d_in[10];

    BranchW3 P;
    for (int i = 0; i < 3; ++i) {
        P.p[i].w1 = (const float*)d_in[11 + 6 * i + 0];
        P.p[i].g1 = (const float*)d_in[11 + 6 * i + 1];
        P.p[i].b1 = (const float*)d_in[11 + 6 * i + 2];
        P.p[i].w2 = (const float*)d_in[11 + 6 * i + 3];
        P.p[i].g2 = (const float*)d_in[11 + 6 * i + 4];
        P.p[i].b2 = (const float*)d_in[11 + 6 * i + 5];
    }
    const float* gru_gw = (const float*)d_in[29];
    const float* gru_gb = (const float*)d_in[30];
    const float* gru_cw = (const float*)d_in[31];
    const float* gru_cg = (const float*)d_in[32];
    const float* gru_cb = (const float*)d_in[33];

    float* out    = (float*)d_out;
    float* dm_out = out + (size_t)3 * B10HW;     // stack(n0,n1,n2) then dm

    float* ws     = (float*)d_ws;
    float* dm_acc = ws;                 // 2*BHWn
    float* s01    = dm_acc + 2 * BHWn;  // 2*BHWn
    float* up     = s01 + 2 * BHWn;     // B10HW
    float* lo     = up + B10HW;         // B10HW
    float* bout   = lo + B10HW;         // 4*B10HW  (d0, d1, cu, cl)

    const float* patt   = f_atts + BHWn;     // f_atts[1]
    const float* parent = f_nodes + B10HW;   // f_nodes[1]

    hipMemsetAsync(dm_acc, 0, (size_t)2 * BHWn * sizeof(float), stream);
    k_bigconv<<<dim3(1152, 2), 256, 0, stream>>>(xh, patt, da_w1, da_g1, da_b1, da_w2, dm_acc);
    k_dm_soft<<<dim3(288), 256, 0, stream>>>(dm_acc, da_b2, patt, dm_out, s01);
    k_uplo<<<dim3(288), 256, 0, stream>>>(p_nodes, p_atts, up, lo);
    k_branch<<<dim3(288, 1, 4), 256, 0, stream>>>(P, parent, h_nodes, s01, up, lo, bout);
    k_gru<<<dim3(288, 3), 256, 0, stream>>>(f_nodes, h_nodes, p_nodes, bout,
                                            gru_gw, gru_gb, gru_cw, gru_cg, gru_cb, out);
}

// Round 3
// 436.474 us; speedup vs baseline: 5.4588x; 5.4588x over previous
//
#include <hip/hip_runtime.h>
#include <cstddef>
#include <cstdint>

constexpr int Bn    = 8;
constexpr int Hn    = 96;
constexpr int Wn    = 96;
constexpr int HWn   = Hn * Wn;       // 9216
constexpr int BHWn  = Bn * HWn;      // 73728
constexpr int B10HW = Bn * 10 * HWn; // 737280

using short8  = __attribute__((ext_vector_type(8))) short;
using ushort8 = __attribute__((ext_vector_type(8))) unsigned short;
using float4v = __attribute__((ext_vector_type(4))) float;

__device__ __forceinline__ unsigned short f2bf(float f) {
    unsigned u = __builtin_bit_cast(unsigned, f);
    u += 0x7FFFu + ((u >> 16) & 1u);   // RNE; inputs are finite
    return (unsigned short)(u >> 16);
}

// ---------------------------------------------------------------------------
// K0: pack da_w1 (OIHW fp32 [256][257][9]) into B-fragment-ready bf16 records:
// wpk[cb(9)][tap(9)][q(16)][lane(64)][j(8)], lane -> co = q*16+(lane&15),
// ci = cb*32 + (lane>>4)*8 + j, zero-padded past ci=256.
// ---------------------------------------------------------------------------
__global__ void k_packw(const float* __restrict__ w1, short* __restrict__ wpk)
{
    const int idx = blockIdx.x * 256 + threadIdx.x;   // 9*9*16*64 = 82944
    if (idx >= 82944) return;
    const int lane = idx & 63;
    const int q    = (idx >> 6) & 15;
    const int ct   = idx >> 10;          // cb*9 + tap
    const int tap  = ct % 9;
    const int cb   = ct / 9;
    const int co   = q * 16 + (lane & 15);
    const int ci0  = cb * 32 + ((lane >> 4) * 8);
    ushort8 v;
    #pragma unroll
    for (int j = 0; j < 8; ++j) {
        const int ci = ci0 + j;
        const float f = (ci < 257) ? w1[((size_t)co * 257 + ci) * 9 + tap] : 0.f;
        v[j] = f2bf(f);
    }
    *(ushort8*)(wpk + (size_t)idx * 8) = v;
}

// ---------------------------------------------------------------------------
// K1: decomp_att conv3x3 257->256 (+BN+ReLU) fused with conv1x1 256->2,
// as bf16 MFMA implicit GEMM. Block: 128 pos (4r x 32c) x 128 co, 4 waves
// in 2x2 (64x64 each). K-loop: 9 cin-chunks of 32 x 9 taps.
// A staged in LDS fragment-ready; B frags loaded straight from packed global.
// ---------------------------------------------------------------------------
__global__ __launch_bounds__(256)
void k_bigconv_mfma(const float* __restrict__ xh, const float* __restrict__ patt,
                    const short* __restrict__ wpk, const float* __restrict__ g1,
                    const float* __restrict__ b1, const float* __restrict__ w2,
                    float* __restrict__ dm_acc)
{
    __shared__ __align__(16) short xs[4 * 204 * 8];   // [g][pos(6x34)][8ci] bf16

    const int tid    = threadIdx.x;
    const int lane   = tid & 63;
    const int wid    = tid >> 6;
    const int wave_m = wid >> 1;          // 0/1 -> m offset 0/64
    const int wave_n = wid & 1;           // 0/1 -> n offset 0/64
    const int bx     = blockIdx.x;
    const int wseg   = bx % 3;
    const int hb     = (bx / 3) % 24;
    const int b      = bx / 72;
    const int h0     = hb * 4, w0 = wseg * 32;
    const int am     = lane & 15;         // m within 16
    const int aq     = lane >> 4;         // quad = k-octet index
    const int qbase  = blockIdx.y * 8 + wave_n * 4;   // co-16-tile index base

    float4v acc[4][4];
    #pragma unroll
    for (int i = 0; i < 4; ++i)
        #pragma unroll
        for (int j = 0; j < 4; ++j)
            acc[i][j] = float4v{0.f, 0.f, 0.f, 0.f};

    // precompute per-mt A positions (row/col within tile)
    int arow[4], acol[4];
    #pragma unroll
    for (int mt = 0; mt < 4; ++mt) {
        const int m = wave_m * 64 + mt * 16 + am;
        arow[mt] = m >> 5;
        acol[mt] = m & 31;
    }

    for (int cb = 0; cb < 9; ++cb) {
        __syncthreads();
        // stage X chunk: wave wid owns k-octet g = wid
        {
            const int g    = wid;
            const int cig0 = cb * 32 + g * 8;
            for (int pos = lane; pos < 204; pos += 64) {
                const int row = pos / 34, col = pos % 34;
                const int hh = h0 - 1 + row, ww = w0 - 1 + col;
                const bool inb = ((unsigned)hh < (unsigned)Hn) & ((unsigned)ww < (unsigned)Wn);
                const int off = hh * Wn + ww;
                ushort8 v;
                #pragma unroll
                for (int j = 0; j < 8; ++j) {
                    const int ci = cig0 + j;
                    float f = 0.f;
                    if (inb && ci < 257)
                        f = (ci == 0) ? patt[b * HWn + off]
                                      : xh[((size_t)b * 256 + (ci - 1)) * HWn + off];
                    v[j] = f2bf(f);
                }
                *(ushort8*)&xs[(g * 204 + pos) * 8] = v;
            }
        }
        __syncthreads();

        const short* wb = wpk + (((size_t)cb * 9) * 16 * 64) * 8;
        for (int tap = 0; tap < 9; ++tap) {
            const int kh = tap / 3, kw = tap % 3;
            // B fragments: coalesced 16B/lane from packed weights (L2)
            short8 bfr[4];
            const short* wt = wb + ((size_t)tap * 16 * 64) * 8;
            #pragma unroll
            for (int nt = 0; nt < 4; ++nt)
                bfr[nt] = *(const short8*)(wt + ((size_t)(qbase + nt) * 64 + lane) * 8);
            // A fragments: one ds_read_b128 each
            short8 afr[4];
            #pragma unroll
            for (int mt = 0; mt < 4; ++mt) {
                const int pos = (arow[mt] + kh) * 34 + (acol[mt] + kw);
                afr[mt] = *(const short8*)&xs[(aq * 204 + pos) * 8];
            }
            #pragma unroll
            for (int mt = 0; mt < 4; ++mt)
                #pragma unroll
                for (int nt = 0; nt < 4; ++nt)
                    acc[mt][nt] = __builtin_amdgcn_mfma_f32_16x16x32_bf16(
                        afr[mt], bfr[nt], acc[mt][nt], 0, 0, 0);
        }
    }

    // epilogue: BN+ReLU, 1x1 (256->2) reduce over n, atomicAdd into dm_acc
    float gv[4], bv[4], wa[4], wbv[4];
    const int ncol = blockIdx.y * 128 + wave_n * 64 + am;
    #pragma unroll
    for (int nt = 0; nt < 4; ++nt) {
        const int co = ncol + nt * 16;
        gv[nt]  = g1[co];
        bv[nt]  = b1[co];
        wa[nt]  = w2[co];
        wbv[nt] = w2[256 + co];
    }
    #pragma unroll
    for (int mt = 0; mt < 4; ++mt) {
        #pragma unroll
        for (int reg = 0; reg < 4; ++reg) {
            float s0 = 0.f, s1 = 0.f;
            #pragma unroll
            for (int nt = 0; nt < 4; ++nt) {
                const float y = fmaxf(fmaf(acc[mt][nt][reg], gv[nt], bv[nt]), 0.f);
                s0 = fmaf(wa[nt], y, s0);
                s1 = fmaf(wbv[nt], y, s1);
            }
            #pragma unroll
            for (int off = 1; off < 16; off <<= 1) {
                s0 += __shfl_xor(s0, off, 64);
                s1 += __shfl_xor(s1, off, 64);
            }
            if (am == 0) {
                const int m = wave_m * 64 + mt * 16 + aq * 4 + reg;
                const int r = m >> 5, c = m & 31;
                const size_t o = (size_t)(b * 2) * HWn + (h0 + r) * Wn + (w0 + c);
                atomicAdd(&dm_acc[o], s0);
                atomicAdd(&dm_acc[o + HWn], s1);
            }
        }
    }
}

// ---------------------------------------------------------------------------
// K2: dm = acc + bias (written to d_out), s_i = softmax(dm)_i * parent_att
// ---------------------------------------------------------------------------
__global__ void k_dm_soft(const float* __restrict__ dm_acc, const float* __restrict__ db2,
                          const float* __restrict__ patt, float* __restrict__ dm_out,
                          float* __restrict__ s01)
{
    const int p = blockIdx.x * 256 + threadIdx.x;
    if (p >= BHWn) return;
    const int b = p / HWn, hw = p % HWn;
    const size_t i0 = (size_t)(b * 2) * HWn + hw;
    const size_t i1 = (size_t)(b * 2 + 1) * HWn + hw;
    float d0 = dm_acc[i0] + db2[0];
    float d1 = dm_acc[i1] + db2[1];
    dm_out[i0] = d0;
    dm_out[i1] = d1;
    float m  = fmaxf(d0, d1);
    float e0 = expf(d0 - m), e1 = expf(d1 - m);
    float pa = patt[p];
    float inv = pa / (e0 + e1);
    s01[p]        = e0 * inv;
    s01[BHWn + p] = e1 * inv;
}

// ---------------------------------------------------------------------------
// K3: up = sum(p_nodes[1:5]) * sum(p_atts[1:5]); lo = sum(p_nodes[5:7]) * sum(p_atts[5:7])
// ---------------------------------------------------------------------------
__global__ void k_uplo(const float* __restrict__ pn, const float* __restrict__ pa,
                       float* __restrict__ up, float* __restrict__ lo)
{
    const int p = blockIdx.x * 256 + threadIdx.x;
    if (p >= BHWn) return;
    const int b = p / HWn, hw = p % HWn;
    float au = 0.f, al = 0.f;
    for (int k = 1; k <= 4; ++k) au += pa[(size_t)(k * Bn + b) * HWn + hw];
    for (int k = 5; k <= 6; ++k) al += pa[(size_t)(k * Bn + b) * HWn + hw];
    for (int c = 0; c < 10; ++c) {
        float su = 0.f, sl = 0.f;
        for (int k = 1; k <= 4; ++k) su += pn[((size_t)(k * Bn + b) * 10 + c) * HWn + hw];
        for (int k = 5; k <= 6; ++k) sl += pn[((size_t)(k * Bn + b) * 10 + c) * HWn + hw];
        up[((size_t)b * 10 + c) * HWn + hw] = su * au;
        lo[((size_t)b * 10 + c) * HWn + hw] = sl * al;
    }
}

// ---------------------------------------------------------------------------
// K4: branch = ReLU(BN(conv3x3 20->10)) -> ReLU(BN(conv1x1 10->10))
// z=0: decomp0 [parent*s0, h1] (rel)   z=1: decomp1 [parent*s1, h2] (rel)
// z=2: comp_u  [h1, up]        (cu)    z=3: comp_l  [h2, lo]        (cl)
// ---------------------------------------------------------------------------
struct BranchW  { const float *w1, *g1, *b1, *w2, *g2, *b2; };
struct BranchW3 { BranchW p[3]; };

__global__ __launch_bounds__(256)
void k_branch(BranchW3 P, const float* __restrict__ parent, const float* __restrict__ h_nodes,
              const float* __restrict__ s01, const float* __restrict__ up,
              const float* __restrict__ lo, float* __restrict__ bout)
{
    const int z  = blockIdx.z;
    const int pi = (z < 2) ? 0 : (z - 1);
    __shared__ float wl[1800], w2l[100], g1l[10], b1l[10], g2l[10], b2l[10];
    const BranchW& Pw = P.p[pi];
    for (int i = threadIdx.x; i < 1800; i += 256) wl[i] = Pw.w1[i];
    if (threadIdx.x < 100) w2l[threadIdx.x] = Pw.w2[threadIdx.x];
    if (threadIdx.x < 10) {
        g1l[threadIdx.x] = Pw.g1[threadIdx.x];
        b1l[threadIdx.x] = Pw.b1[threadIdx.x];
        g2l[threadIdx.x] = Pw.g2[threadIdx.x];
        b2l[threadIdx.x] = Pw.b2[threadIdx.x];
    }
    __syncthreads();

    const int p = blockIdx.x * 256 + threadIdx.x;
    const int b = p / HWn, hw = p % HWn, h = hw / Wn, w = hw % Wn;

    const float* Ab = nullptr;
    const float* sc = nullptr;
    const float* Bb = nullptr;
    if (z == 0)      { Ab = parent; sc = s01;        Bb = h_nodes + (size_t)1 * B10HW; }
    else if (z == 1) { Ab = parent; sc = s01 + BHWn; Bb = h_nodes + (size_t)2 * B10HW; }
    else if (z == 2) { Ab = h_nodes + (size_t)1 * B10HW; Bb = up; }
    else             { Ab = h_nodes + (size_t)2 * B10HW; Bb = lo; }

    float acc[10] = {};
    for (int kh = 0; kh < 3; ++kh) {
        const int hh = h + kh - 1;
        if ((unsigned)hh >= (unsigned)Hn) continue;
        for (int kw = 0; kw < 3; ++kw) {
            const int ww = w + kw - 1;
            if ((unsigned)ww >= (unsigned)Wn) continue;
            const int off = hh * Wn + ww;
            const int tap = kh * 3 + kw;
            const float scv = sc ? sc[b * HWn + off] : 1.f;
            #pragma unroll
            for (int ci = 0; ci < 20; ++ci) {
                float v;
                if (ci < 10) v = Ab[((size_t)b * 10 + ci) * HWn + off] * scv;
                else         v = Bb[((size_t)b * 10 + (ci - 10)) * HWn + off];
                #pragma unroll
                for (int co = 0; co < 10; ++co)
                    acc[co] = fmaf(wl[(co * 20 + ci) * 9 + tap], v, acc[co]);
            }
        }
    }
    float y[10];
    #pragma unroll
    for (int co = 0; co < 10; ++co)
        y[co] = fmaxf(fmaf(acc[co], g1l[co], b1l[co]), 0.f);
    #pragma unroll
    for (int co = 0; co < 10; ++co) {
        float s = 0.f;
        #pragma unroll
        for (int i = 0; i < 10; ++i) s = fmaf(w2l[co * 10 + i], y[i], s);
        s = fmaxf(fmaf(s, g2l[co], b2l[co]), 0.f);
        bout[(size_t)z * B10HW + ((size_t)b * 10 + co) * HWn + hw] = s;
    }
}

// ---------------------------------------------------------------------------
// K5: ConvGRU (1x1 kernels). z = node 0/1/2.
// ---------------------------------------------------------------------------
__global__ void k_gru(const float* __restrict__ f_nodes, const float* __restrict__ h_nodes,
                      const float* __restrict__ p_nodes, const float* __restrict__ bout,
                      const float* __restrict__ gw, const float* __restrict__ gb,
                      const float* __restrict__ cw, const float* __restrict__ cg,
                      const float* __restrict__ cb, float* __restrict__ out)
{
    const int z = blockIdx.y;
    __shared__ float gwl[40], cwl[200], gbl[2], cgl[10], cbl[10];
    if (threadIdx.x < 40)  gwl[threadIdx.x] = gw[z * 40 + threadIdx.x];
    if (threadIdx.x < 200) cwl[threadIdx.x] = cw[z * 200 + threadIdx.x];
    if (threadIdx.x < 2)   gbl[threadIdx.x] = gb[z * 2 + threadIdx.x];
    if (threadIdx.x < 10) {
        cgl[threadIdx.x] = cg[z * 10 + threadIdx.x];
        cbl[threadIdx.x] = cb[z * 10 + threadIdx.x];
    }
    __syncthreads();

    const int p = blockIdx.x * 256 + threadIdx.x;
    const int b = p / HWn, hw = p % HWn;
    float x[10], h[10];
    #pragma unroll
    for (int c = 0; c < 10; ++c) {
        const size_t idx = ((size_t)b * 10 + c) * HWn + hw;
        if (z == 0)      x[c] = f_nodes[idx] + p_nodes[idx];
        else if (z == 1) x[c] = bout[(size_t)2 * B10HW + idx] + bout[idx];
        else             x[c] = bout[(size_t)3 * B10HW + idx] + bout[(size_t)1 * B10HW + idx];
        h[c] = h_nodes[(size_t)z * B10HW + idx];
    }
    float g0 = gbl[0], g1 = gbl[1];
    #pragma unroll
    for (int c = 0; c < 10; ++c) {
        g0 = fmaf(gwl[c],      x[c], g0);
        g0 = fmaf(gwl[10 + c], h[c], g0);
        g1 = fmaf(gwl[20 + c], x[c], g1);
        g1 = fmaf(gwl[30 + c], h[c], g1);
    }
    const float r = 1.f / (1.f + expf(-g0));
    const float u = 1.f / (1.f + expf(-g1));
    #pragma unroll
    for (int o = 0; o < 10; ++o) {
        float s = 0.f;
        #pragma unroll
        for (int c = 0; c < 10; ++c) {
            s = fmaf(cwl[o * 20 + c],      x[c],     s);
            s = fmaf(cwl[o * 20 + 10 + c], r * h[c], s);
        }
        s = fmaxf(fmaf(s, cgl[o], cbl[o]), 0.f);
        out[(size_t)z * B10HW + ((size_t)b * 10 + o) * HWn + hw] =
            (1.f - u) * h[o] + u * s;
    }
}

// ---------------------------------------------------------------------------
extern "C" void kernel_launch(void* const* d_in, const int* in_sizes, int n_in,
                              void* d_out, int out_size, void* d_ws, size_t ws_size,
                              hipStream_t stream)
{
    (void)in_sizes; (void)n_in; (void)out_size; (void)ws_size;

    const float* f_nodes = (const float*)d_in[0];
    const float* h_nodes = (const float*)d_in[1];
    const float* p_nodes = (const float*)d_in[2];
    const float* xh      = (const float*)d_in[3];
    const float* f_atts  = (const float*)d_in[4];
    const float* p_atts  = (const float*)d_in[5];
    const float* da_w1   = (const float*)d_in[6];
    const float* da_g1   = (const float*)d_in[7];
    const float* da_b1   = (const float*)d_in[8];
    const float* da_w2   = (const float*)d_in[9];
    const float* da_b2   = (const float*)d_in[10];

    BranchW3 P;
    for (int i = 0; i < 3; ++i) {
        P.p[i].w1 = (const float*)d_in[11 + 6 * i + 0];
        P.p[i].g1 = (const float*)d_in[11 + 6 * i + 1];
        P.p[i].b1 = (const float*)d_in[11 + 6 * i + 2];
        P.p[i].w2 = (const float*)d_in[11 + 6 * i + 3];
        P.p[i].g2 = (const float*)d_in[11 + 6 * i + 4];
        P.p[i].b2 = (const float*)d_in[11 + 6 * i + 5];
    }
    const float* gru_gw = (const float*)d_in[29];
    const float* gru_gb = (const float*)d_in[30];
    const float* gru_cw = (const float*)d_in[31];
    const float* gru_cg = (const float*)d_in[32];
    const float* gru_cb = (const float*)d_in[33];

    float* out    = (float*)d_out;
    float* dm_out = out + (size_t)3 * B10HW;     // stack(n0,n1,n2) then dm

    float* ws     = (float*)d_ws;
    float* dm_acc = ws;                 // 2*BHWn
    float* s01    = dm_acc + 2 * BHWn;  // 2*BHWn
    float* up     = s01 + 2 * BHWn;     // B10HW
    float* lo     = up + B10HW;         // B10HW
    float* bout   = lo + B10HW;         // 4*B10HW  (d0, d1, cu, cl)
    // wpk (bf16 packed weights, 663552 shorts = 1.33 MB) aliases s01/up:
    // written by k_packw before k_bigconv_mfma; s01/up are written only after.
    short* wpk    = (short*)s01;

    const float* patt   = f_atts + BHWn;     // f_atts[1]
    const float* parent = f_nodes + B10HW;   // f_nodes[1]

    hipMemsetAsync(dm_acc, 0, (size_t)2 * BHWn * sizeof(float), stream);
    k_packw<<<dim3(324), 256, 0, stream>>>(da_w1, wpk);
    k_bigconv_mfma<<<dim3(576, 2), 256, 0, stream>>>(xh, patt, wpk, da_g1, da_b1,
                                                     da_w2, dm_acc);
    k_dm_soft<<<dim3(288), 256, 0, stream>>>(dm_acc, da_b2, patt, dm_out, s01);
    k_uplo<<<dim3(288), 256, 0, stream>>>(p_nodes, p_atts, up, lo);
    k_branch<<<dim3(288, 1, 4), 256, 0, stream>>>(P, parent, h_nodes, s01, up, lo, bout);
    k_gru<<<dim3(288, 3), 256, 0, stream>>>(f_nodes, h_nodes, p_nodes, bout,
                                            gru_gw, gru_gb, gru_cw, gru_cg, gru_cb, out);
}

// Round 4
// 407.623 us; speedup vs baseline: 5.8452x; 1.0708x over previous
//
#include <hip/hip_runtime.h>
#include <cstddef>
#include <cstdint>

constexpr int Bn    = 8;
constexpr int Hn    = 96;
constexpr int Wn    = 96;
constexpr int HWn   = Hn * Wn;       // 9216
constexpr int BHWn  = Bn * HWn;      // 73728
constexpr int B10HW = Bn * 10 * HWn; // 737280

using short8  = __attribute__((ext_vector_type(8))) short;
using ushort8 = __attribute__((ext_vector_type(8))) unsigned short;
using float4v = __attribute__((ext_vector_type(4))) float;

__device__ __forceinline__ unsigned short f2bf(float f) {
    unsigned u = __builtin_bit_cast(unsigned, f);
    u += 0x7FFFu + ((u >> 16) & 1u);   // RNE; inputs are finite
    return (unsigned short)(u >> 16);
}

// ---------------------------------------------------------------------------
// K0: pack da_w1 (OIHW fp32 [256][257][9]) into B-fragment-ready bf16 records:
// wpk[t=cb*9+tap (81)][q(16)][lane(64)][j(8)], lane -> co = q*16+(lane&15),
// ci = cb*32 + (lane>>4)*8 + j, zero-padded past ci=256.
// ---------------------------------------------------------------------------
__global__ void k_packw(const float* __restrict__ w1, short* __restrict__ wpk)
{
    const int idx = blockIdx.x * 256 + threadIdx.x;   // 81*16*64 = 82944
    if (idx >= 82944) return;
    const int lane = idx & 63;
    const int q    = (idx >> 6) & 15;
    const int t    = idx >> 10;          // cb*9 + tap
    const int tap  = t % 9;
    const int cb   = t / 9;
    const int co   = q * 16 + (lane & 15);
    const int ci0  = cb * 32 + ((lane >> 4) * 8);
    ushort8 v;
    #pragma unroll
    for (int j = 0; j < 8; ++j) {
        const int ci = ci0 + j;
        const float f = (ci < 257) ? w1[((size_t)co * 257 + ci) * 9 + tap] : 0.f;
        v[j] = f2bf(f);
    }
    *(ushort8*)(wpk + (size_t)idx * 8) = v;
}

// ---------------------------------------------------------------------------
// K1: conv3x3 257->256 +BN+ReLU + conv1x1 256->2 + softmax + *patt, one block
// owns the FULL co=256 so the reduction, softmax and s01 finish in-block.
// Block: M=128 pos (4r x 32c) x N=256 co, 4 waves 2x2 (wave = 64m x 128n).
// X double-buffered in LDS (bf16, quad-padded); B prefetched to regs from
// packed global (L2-resident 1.33 MB).
// ---------------------------------------------------------------------------
__global__ __launch_bounds__(256, 2)
void k_bigconv2(const float* __restrict__ xh, const float* __restrict__ patt,
                const short* __restrict__ wpk, const float* __restrict__ g1,
                const float* __restrict__ b1, const float* __restrict__ w2,
                const float* __restrict__ db2,
                float* __restrict__ dm_out, float* __restrict__ s01)
{
    __shared__ __align__(16) short xs[2][4][205][8];  // [buf][quad g][pos 6x34][8ci]
    __shared__ float part[2][128][2];                  // [wave_n][m][ch]

    const int tid    = threadIdx.x;
    const int lane   = tid & 63;
    const int wid    = tid >> 6;
    const int wave_m = wid >> 1;
    const int wave_n = wid & 1;
    const int bx     = blockIdx.x;
    const int wseg   = bx % 3;
    const int hb     = (bx / 3) % 24;
    const int b      = bx / 72;
    const int h0     = hb * 4, w0 = wseg * 32;
    const int am     = lane & 15;
    const int aq     = lane >> 4;

    float4v acc[4][8];
    #pragma unroll
    for (int i = 0; i < 4; ++i)
        #pragma unroll
        for (int j = 0; j < 8; ++j)
            acc[i][j] = float4v{0.f, 0.f, 0.f, 0.f};

    int arow[4], acol[4];
    #pragma unroll
    for (int mt = 0; mt < 4; ++mt) {
        const int m = wave_m * 64 + mt * 16 + am;
        arow[mt] = m >> 5;
        acol[mt] = m & 31;
    }

    // ---- X staging lambda: wave wid stages k-octet g=wid of chunk cb ----
    auto stageX = [&](int cb, int buf) {
        const int cig0 = cb * 32 + wid * 8;
        for (int pos = lane; pos < 204; pos += 64) {
            const int row = pos / 34, col = pos % 34;
            const int hh = h0 - 1 + row, ww = w0 - 1 + col;
            const bool inb = ((unsigned)hh < (unsigned)Hn) & ((unsigned)ww < (unsigned)Wn);
            const int off = hh * Wn + ww;
            ushort8 v;
            #pragma unroll
            for (int j = 0; j < 8; ++j) {
                const int ci = cig0 + j;
                float f = 0.f;
                if (inb && ci < 257)
                    f = (ci == 0) ? patt[b * HWn + off]
                                  : xh[((size_t)b * 256 + (ci - 1)) * HWn + off];
                v[j] = f2bf(f);
            }
            *(ushort8*)&xs[buf][wid][pos][0] = v;
        }
    };

    const short8* wp = (const short8*)wpk;
    const int qb = wave_n * 8;

    stageX(0, 0);
    short8 bfr[8], bnx[8];
    #pragma unroll
    for (int nt = 0; nt < 8; ++nt)
        bfr[nt] = wp[(size_t)(qb + nt) * 64 + lane];
    __syncthreads();

    for (int cb = 0; cb < 9; ++cb) {
        const int buf = cb & 1;
        for (int tap = 0; tap < 9; ++tap) {
            const int t = cb * 9 + tap;
            if (t < 80) {
                #pragma unroll
                for (int nt = 0; nt < 8; ++nt)
                    bnx[nt] = wp[((size_t)(t + 1) * 16 + qb + nt) * 64 + lane];
            }
            const int kh = tap / 3, kw = tap % 3;
            short8 afr[4];
            #pragma unroll
            for (int mt = 0; mt < 4; ++mt) {
                const int pos = (arow[mt] + kh) * 34 + (acol[mt] + kw);
                afr[mt] = *(const short8*)&xs[buf][aq][pos][0];
            }
            #pragma unroll
            for (int mt = 0; mt < 4; ++mt)
                #pragma unroll
                for (int nt = 0; nt < 8; ++nt)
                    acc[mt][nt] = __builtin_amdgcn_mfma_f32_16x16x32_bf16(
                        afr[mt], bfr[nt], acc[mt][nt], 0, 0, 0);
            #pragma unroll
            for (int nt = 0; nt < 8; ++nt) bfr[nt] = bnx[nt];
        }
        if (cb < 8) stageX(cb + 1, buf ^ 1);
        __syncthreads();
    }

    // ---- epilogue: BN+ReLU, 1x1 (256->2), in-block reduce, softmax, s01 ----
    float gv[8], bv[8], wa[8], wbv[8];
    #pragma unroll
    for (int nt = 0; nt < 8; ++nt) {
        const int co = wave_n * 128 + nt * 16 + am;
        gv[nt]  = g1[co];
        bv[nt]  = b1[co];
        wa[nt]  = w2[co];
        wbv[nt] = w2[256 + co];
    }
    #pragma unroll
    for (int mt = 0; mt < 4; ++mt) {
        #pragma unroll
        for (int reg = 0; reg < 4; ++reg) {
            float s0 = 0.f, s1 = 0.f;
            #pragma unroll
            for (int nt = 0; nt < 8; ++nt) {
                const float y = fmaxf(fmaf(acc[mt][nt][reg], gv[nt], bv[nt]), 0.f);
                s0 = fmaf(wa[nt], y, s0);
                s1 = fmaf(wbv[nt], y, s1);
            }
            #pragma unroll
            for (int off = 1; off < 16; off <<= 1) {
                s0 += __shfl_xor(s0, off, 64);
                s1 += __shfl_xor(s1, off, 64);
            }
            if (am == 0) {
                const int m = wave_m * 64 + mt * 16 + aq * 4 + reg;
                part[wave_n][m][0] = s0;
                part[wave_n][m][1] = s1;
            }
        }
    }
    __syncthreads();
    if (tid < 128) {
        const int m = tid, r = m >> 5, c = m & 31;
        const int off = (h0 + r) * Wn + (w0 + c);
        float d0 = part[0][m][0] + part[1][m][0] + db2[0];
        float d1 = part[0][m][1] + part[1][m][1] + db2[1];
        dm_out[(size_t)(b * 2) * HWn + off]     = d0;
        dm_out[(size_t)(b * 2 + 1) * HWn + off] = d1;
        const float mx = fmaxf(d0, d1);
        const float e0 = expf(d0 - mx), e1 = expf(d1 - mx);
        const float pa = patt[b * HWn + off];
        const float inv = pa / (e0 + e1);
        s01[b * HWn + off]        = e0 * inv;
        s01[BHWn + b * HWn + off] = e1 * inv;
    }
}

// ---------------------------------------------------------------------------
// K3: up = sum(p_nodes[1:5]) * sum(p_atts[1:5]); lo = sum(p_nodes[5:7]) * sum(p_atts[5:7])
// ---------------------------------------------------------------------------
__global__ void k_uplo(const float* __restrict__ pn, const float* __restrict__ pa,
                       float* __restrict__ up, float* __restrict__ lo)
{
    const int p = blockIdx.x * 256 + threadIdx.x;
    if (p >= BHWn) return;
    const int b = p / HWn, hw = p % HWn;
    float au = 0.f, al = 0.f;
    for (int k = 1; k <= 4; ++k) au += pa[(size_t)(k * Bn + b) * HWn + hw];
    for (int k = 5; k <= 6; ++k) al += pa[(size_t)(k * Bn + b) * HWn + hw];
    for (int c = 0; c < 10; ++c) {
        float su = 0.f, sl = 0.f;
        for (int k = 1; k <= 4; ++k) su += pn[((size_t)(k * Bn + b) * 10 + c) * HWn + hw];
        for (int k = 5; k <= 6; ++k) sl += pn[((size_t)(k * Bn + b) * 10 + c) * HWn + hw];
        up[((size_t)b * 10 + c) * HWn + hw] = su * au;
        lo[((size_t)b * 10 + c) * HWn + hw] = sl * al;
    }
}

// ---------------------------------------------------------------------------
// K4: branch = ReLU(BN(conv3x3 20->10)) -> ReLU(BN(conv1x1 10->10)), tiled.
// Tile 8r x 32c per block; 20-channel halo (10x34) staged in LDS (zero-pad).
// Weights repacked [tap][ci][12] for float4 broadcast reads.
// z=0: [parent*s0, h1](rel)  z=1: [parent*s1, h2](rel)
// z=2: [h1, up](cu)          z=3: [h2, lo](cl)
// ---------------------------------------------------------------------------
struct BranchW  { const float *w1, *g1, *b1, *w2, *g2, *b2; };
struct BranchW3 { BranchW p[3]; };

__global__ __launch_bounds__(256)
void k_branch(BranchW3 P, const float* __restrict__ parent, const float* __restrict__ h_nodes,
              const float* __restrict__ s01, const float* __restrict__ up,
              const float* __restrict__ lo, float* __restrict__ bout)
{
    const int z  = blockIdx.y;
    const int pi = (z < 2) ? 0 : (z - 1);
    __shared__ float xt[20][10][34];                       // 27.2 KB halo tile
    __shared__ __align__(16) float wlt[9 * 20 * 12];       // [tap][ci][co pad12]
    __shared__ float w2l[100], g1l[10], b1l[10], g2l[10], b2l[10];

    const BranchW& Pw = P.p[pi];
    const int tid = threadIdx.x;
    // stage weights
    for (int idx = tid; idx < 2160; idx += 256) {
        const int co = idx % 12, rem = idx / 12, ci = rem % 20, tap = rem / 20;
        wlt[idx] = (co < 10) ? Pw.w1[(co * 20 + ci) * 9 + tap] : 0.f;
    }
    if (tid < 100) w2l[tid] = Pw.w2[tid];
    if (tid < 10) {
        g1l[tid] = Pw.g1[tid]; b1l[tid] = Pw.b1[tid];
        g2l[tid] = Pw.g2[tid]; b2l[tid] = Pw.b2[tid];
    }

    const int bx = blockIdx.x;
    const int tw = bx % 3, th = (bx / 3) % 12, b = bx / 36;
    const int h0 = th * 8, w0 = tw * 32;

    const float* Ab;
    const float* sc = nullptr;
    const float* Bb;
    if (z == 0)      { Ab = parent; sc = s01;        Bb = h_nodes + (size_t)1 * B10HW; }
    else if (z == 1) { Ab = parent; sc = s01 + BHWn; Bb = h_nodes + (size_t)2 * B10HW; }
    else if (z == 2) { Ab = h_nodes + (size_t)1 * B10HW; Bb = up; }
    else             { Ab = h_nodes + (size_t)2 * B10HW; Bb = lo; }

    // stage x halo: 20 ch x 10 rows x 34 cols (z<2: A channels pre-scaled by s01)
    for (int idx = tid; idx < 6800; idx += 256) {
        const int col = idx % 34, rem = idx / 34, row = rem % 10, ch = rem / 10;
        const int hh = h0 - 1 + row, ww = w0 - 1 + col;
        float v = 0.f;
        if (((unsigned)hh < (unsigned)Hn) & ((unsigned)ww < (unsigned)Wn)) {
            const int off = hh * Wn + ww;
            if (ch < 10) {
                v = Ab[((size_t)b * 10 + ch) * HWn + off];
                if (sc) v *= sc[b * HWn + off];
            } else {
                v = Bb[((size_t)b * 10 + (ch - 10)) * HWn + off];
            }
        }
        ((float*)xt)[idx] = v;
    }
    __syncthreads();

    const int r = tid >> 5, c = tid & 31;
    float a0 = 0, a1 = 0, a2 = 0, a3 = 0, a4 = 0, a5 = 0, a6 = 0, a7 = 0, a8 = 0, a9 = 0;
    #pragma unroll
    for (int tap = 0; tap < 9; ++tap) {
        const int kh = tap / 3, kw = tap % 3;
        #pragma unroll
        for (int ci = 0; ci < 20; ++ci) {
            const float xv = xt[ci][r + kh][c + kw];
            const float4 wA = *(const float4*)&wlt[(tap * 20 + ci) * 12];
            const float4 wB = *(const float4*)&wlt[(tap * 20 + ci) * 12 + 4];
            const float2 wC = *(const float2*)&wlt[(tap * 20 + ci) * 12 + 8];
            a0 = fmaf(wA.x, xv, a0); a1 = fmaf(wA.y, xv, a1);
            a2 = fmaf(wA.z, xv, a2); a3 = fmaf(wA.w, xv, a3);
            a4 = fmaf(wB.x, xv, a4); a5 = fmaf(wB.y, xv, a5);
            a6 = fmaf(wB.z, xv, a6); a7 = fmaf(wB.w, xv, a7);
            a8 = fmaf(wC.x, xv, a8); a9 = fmaf(wC.y, xv, a9);
        }
    }
    float acc[10] = {a0, a1, a2, a3, a4, a5, a6, a7, a8, a9};
    float y[10];
    #pragma unroll
    for (int co = 0; co < 10; ++co)
        y[co] = fmaxf(fmaf(acc[co], g1l[co], b1l[co]), 0.f);
    const int hw = (h0 + r) * Wn + (w0 + c);
    #pragma unroll
    for (int co = 0; co < 10; ++co) {
        float s = 0.f;
        #pragma unroll
        for (int i = 0; i < 10; ++i) s = fmaf(w2l[co * 10 + i], y[i], s);
        s = fmaxf(fmaf(s, g2l[co], b2l[co]), 0.f);
        bout[(size_t)z * B10HW + ((size_t)b * 10 + co) * HWn + hw] = s;
    }
}

// ---------------------------------------------------------------------------
// K5: ConvGRU (1x1 kernels). z = node 0/1/2.
// ---------------------------------------------------------------------------
__global__ void k_gru(const float* __restrict__ f_nodes, const float* __restrict__ h_nodes,
                      const float* __restrict__ p_nodes, const float* __restrict__ bout,
                      const float* __restrict__ gw, const float* __restrict__ gb,
                      const float* __restrict__ cw, const float* __restrict__ cg,
                      const float* __restrict__ cb, float* __restrict__ out)
{
    const int z = blockIdx.y;
    __shared__ float gwl[40], cwl[200], gbl[2], cgl[10], cbl[10];
    if (threadIdx.x < 40)  gwl[threadIdx.x] = gw[z * 40 + threadIdx.x];
    if (threadIdx.x < 200) cwl[threadIdx.x] = cw[z * 200 + threadIdx.x];
    if (threadIdx.x < 2)   gbl[threadIdx.x] = gb[z * 2 + threadIdx.x];
    if (threadIdx.x < 10) {
        cgl[threadIdx.x] = cg[z * 10 + threadIdx.x];
        cbl[threadIdx.x] = cb[z * 10 + threadIdx.x];
    }
    __syncthreads();

    const int p = blockIdx.x * 256 + threadIdx.x;
    const int b = p / HWn, hw = p % HWn;
    float x[10], h[10];
    #pragma unroll
    for (int c = 0; c < 10; ++c) {
        const size_t idx = ((size_t)b * 10 + c) * HWn + hw;
        if (z == 0)      x[c] = f_nodes[idx] + p_nodes[idx];
        else if (z == 1) x[c] = bout[(size_t)2 * B10HW + idx] + bout[idx];
        else             x[c] = bout[(size_t)3 * B10HW + idx] + bout[(size_t)1 * B10HW + idx];
        h[c] = h_nodes[(size_t)z * B10HW + idx];
    }
    float g0 = gbl[0], g1 = gbl[1];
    #pragma unroll
    for (int c = 0; c < 10; ++c) {
        g0 = fmaf(gwl[c],      x[c], g0);
        g0 = fmaf(gwl[10 + c], h[c], g0);
        g1 = fmaf(gwl[20 + c], x[c], g1);
        g1 = fmaf(gwl[30 + c], h[c], g1);
    }
    const float r = 1.f / (1.f + expf(-g0));
    const float u = 1.f / (1.f + expf(-g1));
    #pragma unroll
    for (int o = 0; o < 10; ++o) {
        float s = 0.f;
        #pragma unroll
        for (int c = 0; c < 10; ++c) {
            s = fmaf(cwl[o * 20 + c],      x[c],     s);
            s = fmaf(cwl[o * 20 + 10 + c], r * h[c], s);
        }
        s = fmaxf(fmaf(s, cgl[o], cbl[o]), 0.f);
        out[(size_t)z * B10HW + ((size_t)b * 10 + o) * HWn + hw] =
            (1.f - u) * h[o] + u * s;
    }
}

// ---------------------------------------------------------------------------
extern "C" void kernel_launch(void* const* d_in, const int* in_sizes, int n_in,
                              void* d_out, int out_size, void* d_ws, size_t ws_size,
                              hipStream_t stream)
{
    (void)in_sizes; (void)n_in; (void)out_size; (void)ws_size;

    const float* f_nodes = (const float*)d_in[0];
    const float* h_nodes = (const float*)d_in[1];
    const float* p_nodes = (const float*)d_in[2];
    const float* xh      = (const float*)d_in[3];
    const float* f_atts  = (const float*)d_in[4];
    const float* p_atts  = (const float*)d_in[5];
    const float* da_w1   = (const float*)d_in[6];
    const float* da_g1   = (const float*)d_in[7];
    const float* da_b1   = (const float*)d_in[8];
    const float* da_w2   = (const float*)d_in[9];
    const float* da_b2   = (const float*)d_in[10];

    BranchW3 P;
    for (int i = 0; i < 3; ++i) {
        P.p[i].w1 = (const float*)d_in[11 + 6 * i + 0];
        P.p[i].g1 = (const float*)d_in[11 + 6 * i + 1];
        P.p[i].b1 = (const float*)d_in[11 + 6 * i + 2];
        P.p[i].w2 = (const float*)d_in[11 + 6 * i + 3];
        P.p[i].g2 = (const float*)d_in[11 + 6 * i + 4];
        P.p[i].b2 = (const float*)d_in[11 + 6 * i + 5];
    }
    const float* gru_gw = (const float*)d_in[29];
    const float* gru_gb = (const float*)d_in[30];
    const float* gru_cw = (const float*)d_in[31];
    const float* gru_cg = (const float*)d_in[32];
    const float* gru_cb = (const float*)d_in[33];

    float* out    = (float*)d_out;
    float* dm_out = out + (size_t)3 * B10HW;     // stack(n0,n1,n2) then dm

    float* ws     = (float*)d_ws;
    float* s01    = ws;                 // 2*BHWn
    float* up     = s01 + 2 * BHWn;     // B10HW
    float* lo     = up + B10HW;         // B10HW
    float* bout   = lo + B10HW;         // 4*B10HW  (d0, d1, cu, cl)
    // wpk (1.33 MB of bf16) aliases the bout region: written by k_packw,
    // read only by k_bigconv2; bout is written later by k_branch.
    short* wpk    = (short*)bout;

    const float* patt   = f_atts + BHWn;     // f_atts[1]
    const float* parent = f_nodes + B10HW;   // f_nodes[1]

    k_packw<<<dim3(324), 256, 0, stream>>>(da_w1, wpk);
    k_bigconv2<<<dim3(576), 256, 0, stream>>>(xh, patt, wpk, da_g1, da_b1,
                                              da_w2, da_b2, dm_out, s01);
    k_uplo<<<dim3(288), 256, 0, stream>>>(p_nodes, p_atts, up, lo);
    k_branch<<<dim3(288, 4), 256, 0, stream>>>(P, parent, h_nodes, s01, up, lo, bout);
    k_gru<<<dim3(288, 3), 256, 0, stream>>>(f_nodes, h_nodes, p_nodes, bout,
                                            gru_gw, gru_gb, gru_cw, gru_cg, gru_cb, out);
}

// Round 5
// 390.879 us; speedup vs baseline: 6.0956x; 1.0428x over previous
//
#include <hip/hip_runtime.h>
#include <cstddef>
#include <cstdint>

constexpr int Bn    = 8;
constexpr int Hn    = 96;
constexpr int Wn    = 96;
constexpr int HWn   = Hn * Wn;       // 9216
constexpr int BHWn  = Bn * HWn;      // 73728
constexpr int B10HW = Bn * 10 * HWn; // 737280

using short8  = __attribute__((ext_vector_type(8))) short;
using ushort8 = __attribute__((ext_vector_type(8))) unsigned short;
using float4v = __attribute__((ext_vector_type(4))) float;

__device__ __forceinline__ unsigned short f2bf(float f) {
    unsigned u = __builtin_bit_cast(unsigned, f);
    u += 0x7FFFu + ((u >> 16) & 1u);   // RNE; inputs are finite
    return (unsigned short)(u >> 16);
}

// ---------------------------------------------------------------------------
// K0: pack da_w1 (OIHW fp32 [256][257][9]) into B-fragment order, bf16:
// wpk[t=cb*9+tap][q(16)][lane(64)][j(8)], co = q*16+(lane&15),
// ci = cb*32+((lane>>4)&3)*8+j. COALESCED linear read, scattered 2B write.
// K-pad (ci>=257) is zeroed by a preceding memset.
// ---------------------------------------------------------------------------
__global__ void k_packw(const float* __restrict__ w1, short* __restrict__ wpk)
{
    const int idx = blockIdx.x * 256 + threadIdx.x;   // 256*257*9 = 592128
    if (idx >= 592128) return;
    const int co  = idx / 2313;
    const int rem = idx % 2313;
    const int ci  = rem / 9;
    const int tap = rem % 9;
    const int cb  = ci >> 5;
    const int g   = (ci >> 3) & 3;
    const int j   = ci & 7;
    const int q   = co >> 4;
    const int lane = (co & 15) + (g << 4);
    const int t   = cb * 9 + tap;
    wpk[(((size_t)t * 16 + q) * 64 + lane) * 8 + j] = (short)f2bf(w1[idx]);
}

// ---------------------------------------------------------------------------
// K1: conv3x3 257->256 +BN+ReLU + conv1x1 256->2 + softmax + *patt.
// Block: M=64 pos (2r x 32c) x N=256 co, 4 waves, wave = 64m x 64n.
// grid 1152 (8b x 48hb x 3wseg) -> ~4.5 blocks/CU of work, 3 resident.
// X double-buffered in LDS (bf16, quad-padded); B prefetched to regs from
// packed global (L2-resident 1.33 MB). Full-N in-block epilogue.
// ---------------------------------------------------------------------------
__global__ __launch_bounds__(256, 3)
void k_bigconv3(const float* __restrict__ xh, const float* __restrict__ patt,
                const short* __restrict__ wpk, const float* __restrict__ g1,
                const float* __restrict__ b1, const float* __restrict__ w2,
                const float* __restrict__ db2,
                float* __restrict__ dm_out, float* __restrict__ s01)
{
    __shared__ __align__(16) short xs[2][4][137][8];  // [buf][k-octet][pos 4x34 pad][8ci]
    __shared__ float part[4][64][2];                  // [wave][m][ch]

    const int tid  = threadIdx.x;
    const int lane = tid & 63;
    const int wid  = tid >> 6;          // wave id = n-quarter
    const int bx   = blockIdx.x;
    const int wseg = bx % 3;
    const int hb   = (bx / 3) % 48;
    const int b    = bx / 144;
    const int h0   = hb * 2, w0 = wseg * 32;
    const int am   = lane & 15;
    const int aq   = lane >> 4;

    float4v acc[4][4];
    #pragma unroll
    for (int i = 0; i < 4; ++i)
        #pragma unroll
        for (int j = 0; j < 4; ++j)
            acc[i][j] = float4v{0.f, 0.f, 0.f, 0.f};

    int arow[4], acol[4];
    #pragma unroll
    for (int mt = 0; mt < 4; ++mt) {
        const int m = mt * 16 + am;
        arow[mt] = m >> 5;
        acol[mt] = m & 31;
    }

    // wave wid stages k-octet g=wid of chunk cb into buf
    auto stageX = [&](int cb, int buf) {
        const int cig0 = cb * 32 + wid * 8;
        for (int pos = lane; pos < 136; pos += 64) {
            const int row = pos / 34, col = pos % 34;
            const int hh = h0 - 1 + row, ww = w0 - 1 + col;
            const bool inb = ((unsigned)hh < (unsigned)Hn) & ((unsigned)ww < (unsigned)Wn);
            const int off = hh * Wn + ww;
            ushort8 v;
            #pragma unroll
            for (int j = 0; j < 8; ++j) {
                const int ci = cig0 + j;
                float f = 0.f;
                if (inb && ci < 257)
                    f = (ci == 0) ? patt[b * HWn + off]
                                  : xh[((size_t)b * 256 + (ci - 1)) * HWn + off];
                v[j] = f2bf(f);
            }
            *(ushort8*)&xs[buf][wid][pos][0] = v;
        }
    };

    const short8* wp = (const short8*)wpk;
    const int qb = wid * 4;             // this wave's co-16-tile base

    stageX(0, 0);
    short8 bfr[4], bnx[4];
    #pragma unroll
    for (int nt = 0; nt < 4; ++nt)
        bfr[nt] = wp[(size_t)(qb + nt) * 64 + lane];
    __syncthreads();

    for (int cb = 0; cb < 9; ++cb) {
        const int buf = cb & 1;
        for (int tap = 0; tap < 9; ++tap) {
            const int t = cb * 9 + tap;
            if (t < 80) {
                #pragma unroll
                for (int nt = 0; nt < 4; ++nt)
                    bnx[nt] = wp[((size_t)(t + 1) * 16 + qb + nt) * 64 + lane];
            }
            const int kh = tap / 3, kw = tap % 3;
            short8 afr[4];
            #pragma unroll
            for (int mt = 0; mt < 4; ++mt) {
                const int pos = (arow[mt] + kh) * 34 + (acol[mt] + kw);
                afr[mt] = *(const short8*)&xs[buf][aq][pos][0];
            }
            #pragma unroll
            for (int mt = 0; mt < 4; ++mt)
                #pragma unroll
                for (int nt = 0; nt < 4; ++nt)
                    acc[mt][nt] = __builtin_amdgcn_mfma_f32_16x16x32_bf16(
                        afr[mt], bfr[nt], acc[mt][nt], 0, 0, 0);
            #pragma unroll
            for (int nt = 0; nt < 4; ++nt) bfr[nt] = bnx[nt];
        }
        if (cb < 8) stageX(cb + 1, buf ^ 1);
        __syncthreads();
    }

    // epilogue: BN+ReLU, 1x1 (256->2), in-block reduce, softmax, s01
    float gv[4], bv[4], wa[4], wbv[4];
    #pragma unroll
    for (int nt = 0; nt < 4; ++nt) {
        const int co = wid * 64 + nt * 16 + am;
        gv[nt]  = g1[co];
        bv[nt]  = b1[co];
        wa[nt]  = w2[co];
        wbv[nt] = w2[256 + co];
    }
    #pragma unroll
    for (int mt = 0; mt < 4; ++mt) {
        #pragma unroll
        for (int reg = 0; reg < 4; ++reg) {
            float s0 = 0.f, s1 = 0.f;
            #pragma unroll
            for (int nt = 0; nt < 4; ++nt) {
                const float y = fmaxf(fmaf(acc[mt][nt][reg], gv[nt], bv[nt]), 0.f);
                s0 = fmaf(wa[nt], y, s0);
                s1 = fmaf(wbv[nt], y, s1);
            }
            #pragma unroll
            for (int off = 1; off < 16; off <<= 1) {
                s0 += __shfl_xor(s0, off, 64);
                s1 += __shfl_xor(s1, off, 64);
            }
            if (am == 0) {
                const int m = mt * 16 + aq * 4 + reg;
                part[wid][m][0] = s0;
                part[wid][m][1] = s1;
            }
        }
    }
    __syncthreads();
    if (tid < 64) {
        const int m = tid, r = m >> 5, c = m & 31;
        const int off = (h0 + r) * Wn + (w0 + c);
        float d0 = part[0][m][0] + part[1][m][0] + part[2][m][0] + part[3][m][0] + db2[0];
        float d1 = part[0][m][1] + part[1][m][1] + part[2][m][1] + part[3][m][1] + db2[1];
        dm_out[(size_t)(b * 2) * HWn + off]     = d0;
        dm_out[(size_t)(b * 2 + 1) * HWn + off] = d1;
        const float mx = fmaxf(d0, d1);
        const float e0 = expf(d0 - mx), e1 = expf(d1 - mx);
        const float pa = patt[b * HWn + off];
        const float inv = pa / (e0 + e1);
        s01[b * HWn + off]        = e0 * inv;
        s01[BHWn + b * HWn + off] = e1 * inv;
    }
}

// ---------------------------------------------------------------------------
// K3: up/lo sums, float4-vectorized, channel-split grid (72 x 10 blocks).
// ---------------------------------------------------------------------------
__global__ void k_uplo(const float* __restrict__ pn, const float* __restrict__ pa,
                       float* __restrict__ up, float* __restrict__ lo)
{
    const int c = blockIdx.y;
    const int i = blockIdx.x * 256 + threadIdx.x;   // over BHWn/4 = 18432
    if (i >= BHWn / 4) return;
    const int b = i / (HWn / 4), q = i % (HWn / 4);
    const float4v* PA = (const float4v*)pa;
    const float4v* PN = (const float4v*)pn;
    float4v au = {0, 0, 0, 0}, al = {0, 0, 0, 0};
    #pragma unroll
    for (int k = 1; k <= 4; ++k) au += PA[(size_t)(k * Bn + b) * (HWn / 4) + q];
    #pragma unroll
    for (int k = 5; k <= 6; ++k) al += PA[(size_t)(k * Bn + b) * (HWn / 4) + q];
    float4v su = {0, 0, 0, 0}, sl = {0, 0, 0, 0};
    #pragma unroll
    for (int k = 1; k <= 4; ++k) su += PN[((size_t)(k * Bn + b) * 10 + c) * (HWn / 4) + q];
    #pragma unroll
    for (int k = 5; k <= 6; ++k) sl += PN[((size_t)(k * Bn + b) * 10 + c) * (HWn / 4) + q];
    ((float4v*)up)[((size_t)b * 10 + c) * (HWn / 4) + q] = su * au;
    ((float4v*)lo)[((size_t)b * 10 + c) * (HWn / 4) + q] = sl * al;
}

// ---------------------------------------------------------------------------
// K4: branch = ReLU(BN(conv3x3 20->10)) -> ReLU(BN(conv1x1 10->10)), tiled.
// ---------------------------------------------------------------------------
struct BranchW  { const float *w1, *g1, *b1, *w2, *g2, *b2; };
struct BranchW3 { BranchW p[3]; };

__global__ __launch_bounds__(256)
void k_branch(BranchW3 P, const float* __restrict__ parent, const float* __restrict__ h_nodes,
              const float* __restrict__ s01, const float* __restrict__ up,
              const float* __restrict__ lo, float* __restrict__ bout)
{
    const int z  = blockIdx.y;
    const int pi = (z < 2) ? 0 : (z - 1);
    __shared__ float xt[20][10][34];
    __shared__ __align__(16) float wlt[9 * 20 * 12];
    __shared__ float w2l[100], g1l[10], b1l[10], g2l[10], b2l[10];

    const BranchW& Pw = P.p[pi];
    const int tid = threadIdx.x;
    for (int idx = tid; idx < 2160; idx += 256) {
        const int co = idx % 12, rem = idx / 12, ci = rem % 20, tap = rem / 20;
        wlt[idx] = (co < 10) ? Pw.w1[(co * 20 + ci) * 9 + tap] : 0.f;
    }
    if (tid < 100) w2l[tid] = Pw.w2[tid];
    if (tid < 10) {
        g1l[tid] = Pw.g1[tid]; b1l[tid] = Pw.b1[tid];
        g2l[tid] = Pw.g2[tid]; b2l[tid] = Pw.b2[tid];
    }

    const int bx = blockIdx.x;
    const int tw = bx % 3, th = (bx / 3) % 12, b = bx / 36;
    const int h0 = th * 8, w0 = tw * 32;

    const float* Ab;
    const float* sc = nullptr;
    const float* Bb;
    if (z == 0)      { Ab = parent; sc = s01;        Bb = h_nodes + (size_t)1 * B10HW; }
    else if (z == 1) { Ab = parent; sc = s01 + BHWn; Bb = h_nodes + (size_t)2 * B10HW; }
    else if (z == 2) { Ab = h_nodes + (size_t)1 * B10HW; Bb = up; }
    else             { Ab = h_nodes + (size_t)2 * B10HW; Bb = lo; }

    for (int idx = tid; idx < 6800; idx += 256) {
        const int col = idx % 34, rem = idx / 34, row = rem % 10, ch = rem / 10;
        const int hh = h0 - 1 + row, ww = w0 - 1 + col;
        float v = 0.f;
        if (((unsigned)hh < (unsigned)Hn) & ((unsigned)ww < (unsigned)Wn)) {
            const int off = hh * Wn + ww;
            if (ch < 10) {
                v = Ab[((size_t)b * 10 + ch) * HWn + off];
                if (sc) v *= sc[b * HWn + off];
            } else {
                v = Bb[((size_t)b * 10 + (ch - 10)) * HWn + off];
            }
        }
        ((float*)xt)[idx] = v;
    }
    __syncthreads();

    const int r = tid >> 5, c = tid & 31;
    float a0 = 0, a1 = 0, a2 = 0, a3 = 0, a4 = 0, a5 = 0, a6 = 0, a7 = 0, a8 = 0, a9 = 0;
    #pragma unroll
    for (int tap = 0; tap < 9; ++tap) {
        const int kh = tap / 3, kw = tap % 3;
        #pragma unroll
        for (int ci = 0; ci < 20; ++ci) {
            const float xv = xt[ci][r + kh][c + kw];
            const float4 wA = *(const float4*)&wlt[(tap * 20 + ci) * 12];
            const float4 wB = *(const float4*)&wlt[(tap * 20 + ci) * 12 + 4];
            const float2 wC = *(const float2*)&wlt[(tap * 20 + ci) * 12 + 8];
            a0 = fmaf(wA.x, xv, a0); a1 = fmaf(wA.y, xv, a1);
            a2 = fmaf(wA.z, xv, a2); a3 = fmaf(wA.w, xv, a3);
            a4 = fmaf(wB.x, xv, a4); a5 = fmaf(wB.y, xv, a5);
            a6 = fmaf(wB.z, xv, a6); a7 = fmaf(wB.w, xv, a7);
            a8 = fmaf(wC.x, xv, a8); a9 = fmaf(wC.y, xv, a9);
        }
    }
    float acc[10] = {a0, a1, a2, a3, a4, a5, a6, a7, a8, a9};
    float y[10];
    #pragma unroll
    for (int co = 0; co < 10; ++co)
        y[co] = fmaxf(fmaf(acc[co], g1l[co], b1l[co]), 0.f);
    const int hw = (h0 + r) * Wn + (w0 + c);
    #pragma unroll
    for (int co = 0; co < 10; ++co) {
        float s = 0.f;
        #pragma unroll
        for (int i = 0; i < 10; ++i) s = fmaf(w2l[co * 10 + i], y[i], s);
        s = fmaxf(fmaf(s, g2l[co], b2l[co]), 0.f);
        bout[(size_t)z * B10HW + ((size_t)b * 10 + co) * HWn + hw] = s;
    }
}

// ---------------------------------------------------------------------------
// K5: ConvGRU (1x1 kernels). z = node 0/1/2.
// ---------------------------------------------------------------------------
__global__ void k_gru(const float* __restrict__ f_nodes, const float* __restrict__ h_nodes,
                      const float* __restrict__ p_nodes, const float* __restrict__ bout,
                      const float* __restrict__ gw, const float* __restrict__ gb,
                      const float* __restrict__ cw, const float* __restrict__ cg,
                      const float* __restrict__ cb, float* __restrict__ out)
{
    const int z = blockIdx.y;
    __shared__ float gwl[40], cwl[200], gbl[2], cgl[10], cbl[10];
    if (threadIdx.x < 40)  gwl[threadIdx.x] = gw[z * 40 + threadIdx.x];
    if (threadIdx.x < 200) cwl[threadIdx.x] = cw[z * 200 + threadIdx.x];
    if (threadIdx.x < 2)   gbl[threadIdx.x] = gb[z * 2 + threadIdx.x];
    if (threadIdx.x < 10) {
        cgl[threadIdx.x] = cg[z * 10 + threadIdx.x];
        cbl[threadIdx.x] = cb[z * 10 + threadIdx.x];
    }
    __syncthreads();

    const int p = blockIdx.x * 256 + threadIdx.x;
    const int b = p / HWn, hw = p % HWn;
    float x[10], h[10];
    #pragma unroll
    for (int c = 0; c < 10; ++c) {
        const size_t idx = ((size_t)b * 10 + c) * HWn + hw;
        if (z == 0)      x[c] = f_nodes[idx] + p_nodes[idx];
        else if (z == 1) x[c] = bout[(size_t)2 * B10HW + idx] + bout[idx];
        else             x[c] = bout[(size_t)3 * B10HW + idx] + bout[(size_t)1 * B10HW + idx];
        h[c] = h_nodes[(size_t)z * B10HW + idx];
    }
    float g0 = gbl[0], g1 = gbl[1];
    #pragma unroll
    for (int c = 0; c < 10; ++c) {
        g0 = fmaf(gwl[c],      x[c], g0);
        g0 = fmaf(gwl[10 + c], h[c], g0);
        g1 = fmaf(gwl[20 + c], x[c], g1);
        g1 = fmaf(gwl[30 + c], h[c], g1);
    }
    const float r = 1.f / (1.f + expf(-g0));
    const float u = 1.f / (1.f + expf(-g1));
    #pragma unroll
    for (int o = 0; o < 10; ++o) {
        float s = 0.f;
        #pragma unroll
        for (int c = 0; c < 10; ++c) {
            s = fmaf(cwl[o * 20 + c],      x[c],     s);
            s = fmaf(cwl[o * 20 + 10 + c], r * h[c], s);
        }
        s = fmaxf(fmaf(s, cgl[o], cbl[o]), 0.f);
        out[(size_t)z * B10HW + ((size_t)b * 10 + o) * HWn + hw] =
            (1.f - u) * h[o] + u * s;
    }
}

// ---------------------------------------------------------------------------
extern "C" void kernel_launch(void* const* d_in, const int* in_sizes, int n_in,
                              void* d_out, int out_size, void* d_ws, size_t ws_size,
                              hipStream_t stream)
{
    (void)in_sizes; (void)n_in; (void)out_size; (void)ws_size;

    const float* f_nodes = (const float*)d_in[0];
    const float* h_nodes = (const float*)d_in[1];
    const float* p_nodes = (const float*)d_in[2];
    const float* xh      = (const float*)d_in[3];
    const float* f_atts  = (const float*)d_in[4];
    const float* p_atts  = (const float*)d_in[5];
    const float* da_w1   = (const float*)d_in[6];
    const float* da_g1   = (const float*)d_in[7];
    const float* da_b1   = (const float*)d_in[8];
    const float* da_w2   = (const float*)d_in[9];
    const float* da_b2   = (const float*)d_in[10];

    BranchW3 P;
    for (int i = 0; i < 3; ++i) {
        P.p[i].w1 = (const float*)d_in[11 + 6 * i + 0];
        P.p[i].g1 = (const float*)d_in[11 + 6 * i + 1];
        P.p[i].b1 = (const float*)d_in[11 + 6 * i + 2];
        P.p[i].w2 = (const float*)d_in[11 + 6 * i + 3];
        P.p[i].g2 = (const float*)d_in[11 + 6 * i + 4];
        P.p[i].b2 = (const float*)d_in[11 + 6 * i + 5];
    }
    const float* gru_gw = (const float*)d_in[29];
    const float* gru_gb = (const float*)d_in[30];
    const float* gru_cw = (const float*)d_in[31];
    const float* gru_cg = (const float*)d_in[32];
    const float* gru_cb = (const float*)d_in[33];

    float* out    = (float*)d_out;
    float* dm_out = out + (size_t)3 * B10HW;     // stack(n0,n1,n2) then dm

    float* ws     = (float*)d_ws;
    float* s01    = ws;                 // 2*BHWn
    float* up     = s01 + 2 * BHWn;     // B10HW
    float* lo     = up + B10HW;         // B10HW
    float* bout   = lo + B10HW;         // 4*B10HW  (d0, d1, cu, cl)
    // wpk (1.33 MB of bf16) aliases the bout region: zeroed+written before
    // k_bigconv3, read only by it; bout is written later by k_branch.
    short* wpk    = (short*)bout;

    const float* patt   = f_atts + BHWn;     // f_atts[1]
    const float* parent = f_nodes + B10HW;   // f_nodes[1]

    hipMemsetAsync(wpk, 0, (size_t)82944 * 8 * sizeof(short), stream);
    k_packw<<<dim3(2313), 256, 0, stream>>>(da_w1, wpk);
    k_bigconv3<<<dim3(1152), 256, 0, stream>>>(xh, patt, wpk, da_g1, da_b1,
                                               da_w2, da_b2, dm_out, s01);
    k_uplo<<<dim3(72, 10), 256, 0, stream>>>(p_nodes, p_atts, up, lo);
    k_branch<<<dim3(288, 4), 256, 0, stream>>>(P, parent, h_nodes, s01, up, lo, bout);
    k_gru<<<dim3(288, 3), 256, 0, stream>>>(f_nodes, h_nodes, p_nodes, bout,
                                            gru_gw, gru_gb, gru_cg ? gru_cw : gru_cw,
                                            gru_cg, gru_cb, out);
}

// Round 6
// 387.354 us; speedup vs baseline: 6.1511x; 1.0091x over previous
//
#include <hip/hip_runtime.h>
#include <cstddef>
#include <cstdint>

constexpr int Bn    = 8;
constexpr int Hn    = 96;
constexpr int Wn    = 96;
constexpr int HWn   = Hn * Wn;       // 9216
constexpr int BHWn  = Bn * HWn;      // 73728
constexpr int B10HW = Bn * 10 * HWn; // 737280

using short8  = __attribute__((ext_vector_type(8))) short;
using ushort8 = __attribute__((ext_vector_type(8))) unsigned short;
using float4v = __attribute__((ext_vector_type(4))) float;

__device__ __forceinline__ unsigned short f2bf(float f) {
    unsigned u = __builtin_bit_cast(unsigned, f);
    u += 0x7FFFu + ((u >> 16) & 1u);   // RNE; inputs are finite
    return (unsigned short)(u >> 16);
}

// ---------------------------------------------------------------------------
// K0: pack da_w1 (OIHW fp32 [256][257][9]) into B-fragment order, bf16,
// indexed by OUTPUT element (coalesced 2B writes, pad zeroed in-kernel):
// o = ((t*16+q)*64+lane)*8+j ; co = q*16+(lane&15) ; tap = t%9 ;
// ci = (t/9)*32 + ((lane>>4)&3)*8 + j ; zero for ci >= 257.
// ---------------------------------------------------------------------------
__global__ void k_packw(const float* __restrict__ w1, short* __restrict__ wpk)
{
    const int o = blockIdx.x * 256 + threadIdx.x;   // 81*16*64*8 = 663552
    if (o >= 663552) return;
    const int j    = o & 7;
    const int lane = (o >> 3) & 63;
    const int q    = (o >> 9) & 15;
    const int t    = o >> 13;            // 0..80 = cb*9+tap
    const int co   = q * 16 + (lane & 15);
    const int ci   = (t / 9) * 32 + ((lane >> 4) & 3) * 8 + j;
    const int tap  = t % 9;
    const float f  = (ci < 257) ? w1[((size_t)co * 257 + ci) * 9 + tap] : 0.f;
    wpk[o] = (short)f2bf(f);
}

// ---------------------------------------------------------------------------
// K1: conv3x3 257->256 +BN+ReLU + conv1x1 256->2 + softmax + *patt.
// Block: M=64 pos (2r x 32c) x N=256 co, 4 waves, wave = 64m x 64n.
// XCD swizzle: b = bx & 7 -> all blocks of one batch on one XCD, so the
// 1.2 MB xh-slice + 1.33 MB wpk stay L2-resident (4 MB/XCD).
// ---------------------------------------------------------------------------
__global__ __launch_bounds__(256, 3)
void k_bigconv3(const float* __restrict__ xh, const float* __restrict__ patt,
                const short* __restrict__ wpk, const float* __restrict__ g1,
                const float* __restrict__ b1, const float* __restrict__ w2,
                const float* __restrict__ db2,
                float* __restrict__ dm_out, float* __restrict__ s01)
{
    __shared__ __align__(16) short xs[2][4][137][8];  // [buf][k-octet][pos 4x34 pad][8ci]
    __shared__ float part[4][64][2];                  // [wave][m][ch]

    const int tid  = threadIdx.x;
    const int lane = tid & 63;
    const int wid  = tid >> 6;          // wave id = n-quarter
    const int bx   = blockIdx.x;
    const int b    = bx & 7;            // XCD-locality swizzle
    const int r2   = bx >> 3;           // 0..143
    const int wseg = r2 % 3;
    const int hb   = r2 / 3;            // 0..47
    const int h0   = hb * 2, w0 = wseg * 32;
    const int am   = lane & 15;
    const int aq   = lane >> 4;

    float4v acc[4][4];
    #pragma unroll
    for (int i = 0; i < 4; ++i)
        #pragma unroll
        for (int j = 0; j < 4; ++j)
            acc[i][j] = float4v{0.f, 0.f, 0.f, 0.f};

    int arow[4], acol[4];
    #pragma unroll
    for (int mt = 0; mt < 4; ++mt) {
        const int m = mt * 16 + am;
        arow[mt] = m >> 5;
        acol[mt] = m & 31;
    }

    // wave wid stages k-octet g=wid of chunk cb into buf
    auto stageX = [&](int cb, int buf) {
        const int cig0 = cb * 32 + wid * 8;
        for (int pos = lane; pos < 136; pos += 64) {
            const int row = pos / 34, col = pos % 34;
            const int hh = h0 - 1 + row, ww = w0 - 1 + col;
            const bool inb = ((unsigned)hh < (unsigned)Hn) & ((unsigned)ww < (unsigned)Wn);
            const int off = hh * Wn + ww;
            ushort8 v;
            #pragma unroll
            for (int j = 0; j < 8; ++j) {
                const int ci = cig0 + j;
                float f = 0.f;
                if (inb && ci < 257)
                    f = (ci == 0) ? patt[b * HWn + off]
                                  : xh[((size_t)b * 256 + (ci - 1)) * HWn + off];
                v[j] = f2bf(f);
            }
            *(ushort8*)&xs[buf][wid][pos][0] = v;
        }
    };

    const short8* wp = (const short8*)wpk;
    const int qb = wid * 4;             // this wave's co-16-tile base

    stageX(0, 0);
    short8 bfr[4], bnx[4];
    #pragma unroll
    for (int nt = 0; nt < 4; ++nt)
        bfr[nt] = wp[(size_t)(qb + nt) * 64 + lane];
    __syncthreads();

    for (int cb = 0; cb < 9; ++cb) {
        const int buf = cb & 1;
        for (int tap = 0; tap < 9; ++tap) {
            const int t = cb * 9 + tap;
            if (t < 80) {
                #pragma unroll
                for (int nt = 0; nt < 4; ++nt)
                    bnx[nt] = wp[((size_t)(t + 1) * 16 + qb + nt) * 64 + lane];
            }
            const int kh = tap / 3, kw = tap % 3;
            short8 afr[4];
            #pragma unroll
            for (int mt = 0; mt < 4; ++mt) {
                const int pos = (arow[mt] + kh) * 34 + (acol[mt] + kw);
                afr[mt] = *(const short8*)&xs[buf][aq][pos][0];
            }
            #pragma unroll
            for (int mt = 0; mt < 4; ++mt)
                #pragma unroll
                for (int nt = 0; nt < 4; ++nt)
                    acc[mt][nt] = __builtin_amdgcn_mfma_f32_16x16x32_bf16(
                        afr[mt], bfr[nt], acc[mt][nt], 0, 0, 0);
            #pragma unroll
            for (int nt = 0; nt < 4; ++nt) bfr[nt] = bnx[nt];
        }
        if (cb < 8) stageX(cb + 1, buf ^ 1);
        __syncthreads();
    }

    // epilogue: BN+ReLU, 1x1 (256->2), in-block reduce, softmax, s01
    float gv[4], bv[4], wa[4], wbv[4];
    #pragma unroll
    for (int nt = 0; nt < 4; ++nt) {
        const int co = wid * 64 + nt * 16 + am;
        gv[nt]  = g1[co];
        bv[nt]  = b1[co];
        wa[nt]  = w2[co];
        wbv[nt] = w2[256 + co];
    }
    #pragma unroll
    for (int mt = 0; mt < 4; ++mt) {
        #pragma unroll
        for (int reg = 0; reg < 4; ++reg) {
            float s0 = 0.f, s1 = 0.f;
            #pragma unroll
            for (int nt = 0; nt < 4; ++nt) {
                const float y = fmaxf(fmaf(acc[mt][nt][reg], gv[nt], bv[nt]), 0.f);
                s0 = fmaf(wa[nt], y, s0);
                s1 = fmaf(wbv[nt], y, s1);
            }
            #pragma unroll
            for (int off = 1; off < 16; off <<= 1) {
                s0 += __shfl_xor(s0, off, 64);
                s1 += __shfl_xor(s1, off, 64);
            }
            if (am == 0) {
                const int m = mt * 16 + aq * 4 + reg;
                part[wid][m][0] = s0;
                part[wid][m][1] = s1;
            }
        }
    }
    __syncthreads();
    if (tid < 64) {
        const int m = tid, r = m >> 5, c = m & 31;
        const int off = (h0 + r) * Wn + (w0 + c);
        float d0 = part[0][m][0] + part[1][m][0] + part[2][m][0] + part[3][m][0] + db2[0];
        float d1 = part[0][m][1] + part[1][m][1] + part[2][m][1] + part[3][m][1] + db2[1];
        dm_out[(size_t)(b * 2) * HWn + off]     = d0;
        dm_out[(size_t)(b * 2 + 1) * HWn + off] = d1;
        const float mx = fmaxf(d0, d1);
        const float e0 = expf(d0 - mx), e1 = expf(d1 - mx);
        const float pa = patt[b * HWn + off];
        const float inv = pa / (e0 + e1);
        s01[b * HWn + off]        = e0 * inv;
        s01[BHWn + b * HWn + off] = e1 * inv;
    }
}

// ---------------------------------------------------------------------------
// K4: branch = ReLU(BN(conv3x3 20->10)) -> ReLU(BN(conv1x1 10->10)), tiled,
// with up/lo composition FUSED into staging (k_uplo eliminated):
// z=0: [parent*s0, h1](rel)  z=1: [parent*s1, h2](rel)
// z=2: [h1, (sum pn 1..4)*(sum pa 1..4)](cu)
// z=3: [h2, (sum pn 5..6)*(sum pa 5..6)](cl)
// ---------------------------------------------------------------------------
struct BranchW  { const float *w1, *g1, *b1, *w2, *g2, *b2; };
struct BranchW3 { BranchW p[3]; };

__global__ __launch_bounds__(256)
void k_branch(BranchW3 P, const float* __restrict__ parent, const float* __restrict__ h_nodes,
              const float* __restrict__ s01, const float* __restrict__ pn,
              const float* __restrict__ pa, float* __restrict__ bout)
{
    const int z  = blockIdx.y;
    const int pi = (z < 2) ? 0 : (z - 1);
    __shared__ float xt[20][10][34];
    __shared__ float paSum[340];
    __shared__ __align__(16) float wlt[9 * 20 * 12];
    __shared__ float w2l[100], g1l[10], b1l[10], g2l[10], b2l[10];

    const BranchW& Pw = P.p[pi];
    const int tid = threadIdx.x;
    for (int idx = tid; idx < 2160; idx += 256) {
        const int co = idx % 12, rem = idx / 12, ci = rem % 20, tap = rem / 20;
        wlt[idx] = (co < 10) ? Pw.w1[(co * 20 + ci) * 9 + tap] : 0.f;
    }
    if (tid < 100) w2l[tid] = Pw.w2[tid];
    if (tid < 10) {
        g1l[tid] = Pw.g1[tid]; b1l[tid] = Pw.b1[tid];
        g2l[tid] = Pw.g2[tid]; b2l[tid] = Pw.b2[tid];
    }

    const int bx = blockIdx.x;
    const int tw = bx % 3, th = (bx / 3) % 12, b = bx / 36;
    const int h0 = th * 8, w0 = tw * 32;

    const float* Ab;            // channels 0..9
    const float* sc = nullptr;  // softmax scale for z<2
    const float* Bb = nullptr;  // channels 10..19 (direct) for z<2
    int k0 = 0, k1 = -1;        // pn/pa slice range for z>=2
    if (z == 0)      { Ab = parent; sc = s01;        Bb = h_nodes + (size_t)1 * B10HW; }
    else if (z == 1) { Ab = parent; sc = s01 + BHWn; Bb = h_nodes + (size_t)2 * B10HW; }
    else if (z == 2) { Ab = h_nodes + (size_t)1 * B10HW; k0 = 1; k1 = 4; }
    else             { Ab = h_nodes + (size_t)2 * B10HW; k0 = 5; k1 = 6; }

    // phase A (z>=2): per-pixel sum of p_atts over the slice range
    if (z >= 2) {
        for (int idx = tid; idx < 340; idx += 256) {
            const int col = idx % 34, row = idx / 34;
            const int hh = h0 - 1 + row, ww = w0 - 1 + col;
            float s = 0.f;
            if (((unsigned)hh < (unsigned)Hn) & ((unsigned)ww < (unsigned)Wn)) {
                const int off = hh * Wn + ww;
                for (int k = k0; k <= k1; ++k)
                    s += pa[(size_t)(k * Bn + b) * HWn + off];
            }
            paSum[idx] = s;
        }
    }
    __syncthreads();

    // phase B: stage x halo 20ch x 10r x 34c
    for (int idx = tid; idx < 6800; idx += 256) {
        const int col = idx % 34, rem = idx / 34, row = rem % 10, ch = rem / 10;
        const int hh = h0 - 1 + row, ww = w0 - 1 + col;
        float v = 0.f;
        if (((unsigned)hh < (unsigned)Hn) & ((unsigned)ww < (unsigned)Wn)) {
            const int off = hh * Wn + ww;
            if (ch < 10) {
                v = Ab[((size_t)b * 10 + ch) * HWn + off];
                if (sc) v *= sc[b * HWn + off];
            } else if (z < 2) {
                v = Bb[((size_t)b * 10 + (ch - 10)) * HWn + off];
            } else {
                float s = 0.f;
                for (int k = k0; k <= k1; ++k)
                    s += pn[((size_t)(k * Bn + b) * 10 + (ch - 10)) * HWn + off];
                v = s * paSum[row * 34 + col];
            }
        }
        ((float*)xt)[idx] = v;
    }
    __syncthreads();

    const int r = tid >> 5, c = tid & 31;
    float a0 = 0, a1 = 0, a2 = 0, a3 = 0, a4 = 0, a5 = 0, a6 = 0, a7 = 0, a8 = 0, a9 = 0;
    #pragma unroll
    for (int tap = 0; tap < 9; ++tap) {
        const int kh = tap / 3, kw = tap % 3;
        #pragma unroll
        for (int ci = 0; ci < 20; ++ci) {
            const float xv = xt[ci][r + kh][c + kw];
            const float4 wA = *(const float4*)&wlt[(tap * 20 + ci) * 12];
            const float4 wB = *(const float4*)&wlt[(tap * 20 + ci) * 12 + 4];
            const float2 wC = *(const float2*)&wlt[(tap * 20 + ci) * 12 + 8];
            a0 = fmaf(wA.x, xv, a0); a1 = fmaf(wA.y, xv, a1);
            a2 = fmaf(wA.z, xv, a2); a3 = fmaf(wA.w, xv, a3);
            a4 = fmaf(wB.x, xv, a4); a5 = fmaf(wB.y, xv, a5);
            a6 = fmaf(wB.z, xv, a6); a7 = fmaf(wB.w, xv, a7);
            a8 = fmaf(wC.x, xv, a8); a9 = fmaf(wC.y, xv, a9);
        }
    }
    float acc[10] = {a0, a1, a2, a3, a4, a5, a6, a7, a8, a9};
    float y[10];
    #pragma unroll
    for (int co = 0; co < 10; ++co)
        y[co] = fmaxf(fmaf(acc[co], g1l[co], b1l[co]), 0.f);
    const int hw = (h0 + r) * Wn + (w0 + c);
    #pragma unroll
    for (int co = 0; co < 10; ++co) {
        float s = 0.f;
        #pragma unroll
        for (int i = 0; i < 10; ++i) s = fmaf(w2l[co * 10 + i], y[i], s);
        s = fmaxf(fmaf(s, g2l[co], b2l[co]), 0.f);
        bout[(size_t)z * B10HW + ((size_t)b * 10 + co) * HWn + hw] = s;
    }
}

// ---------------------------------------------------------------------------
// K5: ConvGRU (1x1 kernels). z = node 0/1/2.
// ---------------------------------------------------------------------------
__global__ void k_gru(const float* __restrict__ f_nodes, const float* __restrict__ h_nodes,
                      const float* __restrict__ p_nodes, const float* __restrict__ bout,
                      const float* __restrict__ gw, const float* __restrict__ gb,
                      const float* __restrict__ cw, const float* __restrict__ cg,
                      const float* __restrict__ cb, float* __restrict__ out)
{
    const int z = blockIdx.y;
    __shared__ float gwl[40], cwl[200], gbl[2], cgl[10], cbl[10];
    if (threadIdx.x < 40)  gwl[threadIdx.x] = gw[z * 40 + threadIdx.x];
    if (threadIdx.x < 200) cwl[threadIdx.x] = cw[z * 200 + threadIdx.x];
    if (threadIdx.x < 2)   gbl[threadIdx.x] = gb[z * 2 + threadIdx.x];
    if (threadIdx.x < 10) {
        cgl[threadIdx.x] = cg[z * 10 + threadIdx.x];
        cbl[threadIdx.x] = cb[z * 10 + threadIdx.x];
    }
    __syncthreads();

    const int p = blockIdx.x * 256 + threadIdx.x;
    const int b = p / HWn, hw = p % HWn;
    float x[10], h[10];
    #pragma unroll
    for (int c = 0; c < 10; ++c) {
        const size_t idx = ((size_t)b * 10 + c) * HWn + hw;
        if (z == 0)      x[c] = f_nodes[idx] + p_nodes[idx];
        else if (z == 1) x[c] = bout[(size_t)2 * B10HW + idx] + bout[idx];
        else             x[c] = bout[(size_t)3 * B10HW + idx] + bout[(size_t)1 * B10HW + idx];
        h[c] = h_nodes[(size_t)z * B10HW + idx];
    }
    float g0 = gbl[0], g1 = gbl[1];
    #pragma unroll
    for (int c = 0; c < 10; ++c) {
        g0 = fmaf(gwl[c],      x[c], g0);
        g0 = fmaf(gwl[10 + c], h[c], g0);
        g1 = fmaf(gwl[20 + c], x[c], g1);
        g1 = fmaf(gwl[30 + c], h[c], g1);
    }
    const float r = 1.f / (1.f + expf(-g0));
    const float u = 1.f / (1.f + expf(-g1));
    #pragma unroll
    for (int o = 0; o < 10; ++o) {
        float s = 0.f;
        #pragma unroll
        for (int c = 0; c < 10; ++c) {
            s = fmaf(cwl[o * 20 + c],      x[c],     s);
            s = fmaf(cwl[o * 20 + 10 + c], r * h[c], s);
        }
        s = fmaxf(fmaf(s, cgl[o], cbl[o]), 0.f);
        out[(size_t)z * B10HW + ((size_t)b * 10 + o) * HWn + hw] =
            (1.f - u) * h[o] + u * s;
    }
}

// ---------------------------------------------------------------------------
extern "C" void kernel_launch(void* const* d_in, const int* in_sizes, int n_in,
                              void* d_out, int out_size, void* d_ws, size_t ws_size,
                              hipStream_t stream)
{
    (void)in_sizes; (void)n_in; (void)out_size; (void)ws_size;

    const float* f_nodes = (const float*)d_in[0];
    const float* h_nodes = (const float*)d_in[1];
    const float* p_nodes = (const float*)d_in[2];
    const float* xh      = (const float*)d_in[3];
    const float* f_atts  = (const float*)d_in[4];
    const float* p_atts  = (const float*)d_in[5];
    const float* da_w1   = (const float*)d_in[6];
    const float* da_g1   = (const float*)d_in[7];
    const float* da_b1   = (const float*)d_in[8];
    const float* da_w2   = (const float*)d_in[9];
    const float* da_b2   = (const float*)d_in[10];

    BranchW3 P;
    for (int i = 0; i < 3; ++i) {
        P.p[i].w1 = (const float*)d_in[11 + 6 * i + 0];
        P.p[i].g1 = (const float*)d_in[11 + 6 * i + 1];
        P.p[i].b1 = (const float*)d_in[11 + 6 * i + 2];
        P.p[i].w2 = (const float*)d_in[11 + 6 * i + 3];
        P.p[i].g2 = (const float*)d_in[11 + 6 * i + 4];
        P.p[i].b2 = (const float*)d_in[11 + 6 * i + 5];
    }
    const float* gru_gw = (const float*)d_in[29];
    const float* gru_gb = (const float*)d_in[30];
    const float* gru_cw = (const float*)d_in[31];
    const float* gru_cg = (const float*)d_in[32];
    const float* gru_cb = (const float*)d_in[33];

    float* out    = (float*)d_out;
    float* dm_out = out + (size_t)3 * B10HW;     // stack(n0,n1,n2) then dm

    float* ws     = (float*)d_ws;
    float* s01    = ws;                 // 2*BHWn
    float* bout   = s01 + 2 * BHWn;     // 4*B10HW  (d0, d1, cu, cl)
    // wpk (1.33 MB of bf16) aliases the bout region: written by k_packw,
    // read only by k_bigconv3; bout is written later by k_branch.
    short* wpk    = (short*)bout;

    const float* patt   = f_atts + BHWn;     // f_atts[1]
    const float* parent = f_nodes + B10HW;   // f_nodes[1]

    k_packw<<<dim3(2592), 256, 0, stream>>>(da_w1, wpk);
    k_bigconv3<<<dim3(1152), 256, 0, stream>>>(xh, patt, wpk, da_g1, da_b1,
                                               da_w2, da_b2, dm_out, s01);
    k_branch<<<dim3(288, 4), 256, 0, stream>>>(P, parent, h_nodes, s01,
                                               p_nodes, p_atts, bout);
    k_gru<<<dim3(288, 3), 256, 0, stream>>>(f_nodes, h_nodes, p_nodes, bout,
                                            gru_gw, gru_gb, gru_cw, gru_cg, gru_cb, out);
}